// Round 5
// baseline (834.741 us; speedup 1.0000x reference)
//
#include <hip/hip_runtime.h>

typedef unsigned short ushort_t;

#define NVOX 4096
#define NSV  256
#define XD   128
#define YD   128
#define ZD   16
#define CD   128
#define NCD  20
#define HD   8
#define DHD  16
#define MAPN 524288
#define EPSF 1e-5f
#define NBLK 512

// ---- fp32 arena offsets (floats) ----
#define OF_FEAT 0
#define OF_CW1  524288
#define OF_CB1  540672
#define OF_CG1  540800
#define OF_CBE1 540928
#define OF_CW2  541056
#define OF_CB2  557440
#define OF_PW1  557568
#define OF_PB1  557760
#define OF_PG1  557824
#define OF_PBE1 557888
#define OF_PW2  557952
#define OF_PB2  558016
#define OF_WQ   558080
#define OF_BQ   574464
#define OF_WK   574592
#define OF_BK   590976
#define OF_WV   591104
#define OF_BV   607488
#define OF_WO   607616
#define OF_BO   624000
#define OF_LNG  624128
#define OF_LNB  624256
#define OF_SEGW 624384
#define OF_SEGB 693504
#define ARENA_N 693568
#define TOTCVT  624341   /* segw excluded (transposed separately) */

__device__ __forceinline__ float bf2f(const ushort_t* p){
  return __uint_as_float(((unsigned)(*p)) << 16);
}
__device__ __forceinline__ ushort_t f2bf(float f){
  unsigned u = __float_as_uint(f);
  u += 0x7fffu + ((u >> 16) & 1u);
  return (ushort_t)(u >> 16);
}
__device__ __forceinline__ unsigned pack2(float a, float b){
  return (unsigned)f2bf(a) | ((unsigned)f2bf(b) << 16);
}
__device__ __forceinline__ float unlo(unsigned u){ return __uint_as_float(u << 16); }
__device__ __forceinline__ float unhi(unsigned u){ return __uint_as_float(u & 0xffff0000u); }

struct SrcPtrs { const void* p[25]; };

__device__ const int g_cnt[25] = {524288,16384,128,128,128,16384,128,192,64,64,64,64,1,
                                  16384,128,16384,128,16384,128,16384,128,128,128,0,20};
__device__ const int g_off[25] = {OF_FEAT,OF_CW1,OF_CB1,OF_CG1,OF_CBE1,OF_CW2,OF_CB2,
                                  OF_PW1,OF_PB1,OF_PG1,OF_PBE1,OF_PW2,OF_PB2,
                                  OF_WQ,OF_BQ,OF_WK,OF_BK,OF_WV,OF_BV,OF_WO,OF_BO,
                                  OF_LNG,OF_LNB,OF_SEGW,OF_SEGB};

// grid barrier: release-fence, device-scope arrive, poll, acquire-fence
__device__ __forceinline__ void gbar(int* bar){
  __syncthreads();
  __threadfence();
  if (threadIdx.x == 0){
    __hip_atomic_fetch_add(bar, 1, __ATOMIC_ACQ_REL, __HIP_MEMORY_SCOPE_AGENT);
    while (__hip_atomic_load(bar, __ATOMIC_ACQUIRE, __HIP_MEMORY_SCOPE_AGENT) < NBLK)
      __builtin_amdgcn_s_sleep(8);
  }
  __syncthreads();
  __threadfence();
}

__global__ void kinit(int* bars){ if (threadIdx.x < 8) bars[threadIdx.x] = 0; }

struct S2 { unsigned bitmap[256]; int scnt[256]; int chunkpref[256]; int smom[18]; int keys[NVOX]; };
struct SQ { float frows[16][CD]; };
struct S34 { float part[4][CD]; float row[CD]; float cpar[2][CD]; };
struct S6 { float row[CD]; float cpar[2][CD]; float hrow[CD]; };
struct S9 { float ubuf[1152];          // q as [g*128+c] (ph A) / ctxT stride-9 [c*9+g] (ph B)
            float e8T[64][8]; float cpart[2][8][CD];
            unsigned sc2[32][NSV+1];
            float saf[3][64]; float ssc[64]; float w2s[64]; float rinv[64]; };
struct S10 { int sco4[8][4]; int jn[8][27]; float partial[4][8][NCD]; };
union __align__(16) USM { S2 s2; SQ sq; S34 s34; S6 s6; S9 s9; S10 s10; };

__global__ __launch_bounds__(256, 2) void kfused(SrcPtrs sp, const int* idx, int* bars,
    float* arena, float* wt, int* map, int* seg, float* afold_g, float* scfold_g,
    int* uxyz, float* t1, float* bnsum, float* bnsq, float* kb, float* vb,
    float* qb, float* yb, void* outv)
{
  __shared__ USM sm;
  __shared__ int sm_flag;
  int t = threadIdx.x, b = blockIdx.x;
  const float* A = arena;

  // ================= stage 0: dtype flag + arena convert + map init + wt transpose
  if (t < 64){
    const ushort_t* f16 = (const ushort_t*)sp.p[0];
    unsigned u = f16[2*t];
    int e = (u >> 7) & 0xFF;
    int sane = (u == 0 || (e >= 90 && e <= 150)) ? 1 : 0;
    unsigned long long bl = __ballot(sane);
    if (t == 0) sm_flag = (__popcll(bl) >= 48) ? 1 : 0;
  }
  __syncthreads();
  const int fl = sm_flag;
  {
    int gid = b*256 + t;
    const int GS = NBLK*256;
    for (int k=gid; k<MAPN; k+=GS) map[k] = -1;
    if (gid < CD){ bnsum[gid]=0.f; bnsq[gid]=0.f; }
    for (int el=gid; el<TOTCVT; el+=GS){
      int s=0, rem=el;
      while (rem >= g_cnt[s]){ rem -= g_cnt[s]; ++s; }
      float v = fl ? bf2f((const ushort_t*)sp.p[s] + rem) : ((const float*)sp.p[s])[rem];
      arena[g_off[s]+rem] = v;
    }
    const ushort_t* swb = (const ushort_t*)sp.p[23];
    const float*    swf = (const float*)sp.p[23];
    for (int k=gid; k<27*NCD*CD; k+=GS){
      int nb = k/(NCD*CD); int rem = k - nb*(NCD*CD); int o = rem/CD, i = rem - o*CD;
      int src = nb*(CD*NCD) + i*NCD + o;
      wt[k] = fl ? bf2f(swb+src) : swf[src];
    }
  }
  gbar(bars+0);

  // ================= stage 1: block 0 = unique+BN-fold; blocks 256-511 = q-proj
  if (b == 0){
    sm.s2.bitmap[t] = 0;
    if (t < 18) sm.s2.smom[t] = 0;
    __syncthreads();
    int sacc[9] = {0,0,0,0,0,0,0,0,0};
    for (int v = t; v < NVOX; v += 256){
      int4 q = ((const int4*)idx)[v];
      int key = q.x*4096 + (q.y>>2)*128 + (q.z>>2)*4 + (q.w>>2);
      sm.s2.keys[v] = key;
      atomicOr(&sm.s2.bitmap[key>>5], 1u << (key&31));
      map[((q.x*XD + q.y)*YD + q.z)*ZD + q.w] = v;
      sacc[0]+=q.y; sacc[1]+=q.z; sacc[2]+=q.w;
      sacc[3]+=q.y*q.y; sacc[4]+=q.z*q.z; sacc[5]+=q.w*q.w;
      sacc[6]+=q.y*q.z; sacc[7]+=q.y*q.w; sacc[8]+=q.z*q.w;
    }
    for (int i=0;i<9;++i) atomicAdd(&sm.s2.smom[9+i], sacc[i]);
    __syncthreads();
    int cnt = __popc(sm.s2.bitmap[t]);
    sm.s2.scnt[t] = cnt;
    __syncthreads();
    for (int off=1; off<256; off<<=1){
      int v = (t >= off) ? sm.s2.scnt[t-off] : 0;
      __syncthreads();
      sm.s2.scnt[t] += v;
      __syncthreads();
    }
    int r = sm.s2.scnt[t] - cnt;
    sm.s2.chunkpref[t] = r;
    int um[9] = {0,0,0,0,0,0,0,0,0};
    {
      unsigned bits = sm.s2.bitmap[t];
      while (bits){
        int bpos = __ffs(bits) - 1;
        bits &= bits - 1;
        int key = t*32 + bpos;
        int gx=(key>>7)&31, gy=(key>>2)&31, gz=key&3;
        uxyz[r] = gx | (gy<<8) | (gz<<16);
        um[0]+=gx; um[1]+=gy; um[2]+=gz;
        um[3]+=gx*gx; um[4]+=gy*gy; um[5]+=gz*gz;
        um[6]+=gx*gy; um[7]+=gx*gz; um[8]+=gy*gz;
        ++r;
      }
    }
    for (int i=0;i<9;++i) atomicAdd(&sm.s2.smom[i], um[i]);
    __syncthreads();
    if (t < 64){
      int* smom = sm.s2.smom;
      double U1[3]={(double)smom[0],(double)smom[1],(double)smom[2]};
      double S1[3]={(double)smom[9],(double)smom[10],(double)smom[11]};
      double Uxx[3][3], Sxx[3][3];
      Uxx[0][0]=smom[3]; Uxx[1][1]=smom[4]; Uxx[2][2]=smom[5];
      Uxx[0][1]=Uxx[1][0]=smom[6]; Uxx[0][2]=Uxx[2][0]=smom[7]; Uxx[1][2]=Uxx[2][1]=smom[8];
      Sxx[0][0]=smom[12]; Sxx[1][1]=smom[13]; Sxx[2][2]=smom[14];
      Sxx[0][1]=Sxx[1][0]=smom[15]; Sxx[0][2]=Sxx[2][0]=smom[16]; Sxx[1][2]=Sxx[2][1]=smom[17];
      double M1[3], M2[3][3];
      for (int a=0;a<3;++a) M1[a] = 256.0*S1[a] - 4096.0*U1[a];
      for (int a=0;a<3;++a)
        for (int b2=0;b2<3;++b2)
          M2[a][b2] = 256.0*Sxx[a][b2] - S1[a]*U1[b2] - S1[b2]*U1[a] + 4096.0*Uxx[a][b2];
      double wv_[3]={(double)A[OF_PW1+t],(double)A[OF_PW1+64+t],(double)A[OF_PW1+128+t]};
      double bj=(double)A[OF_PB1+t], gj=(double)A[OF_PG1+t], bej=(double)A[OF_PBE1+t];
      double Mw=0.0, wMw=0.0;
      for (int a=0;a<3;++a){
        Mw += M1[a]*wv_[a];
        for (int b2=0;b2<3;++b2) wMw += wv_[a]*M2[a][b2]*wv_[b2];
      }
      const double NM = 1048576.0;
      double mean = Mw/NM + bj;
      double Ey2  = wMw/NM + 2.0*bj*Mw/NM + bj*bj;
      double var  = Ey2 - mean*mean;
      double scale = gj / sqrt(var + 1e-5);
      afold_g[t]      = (float)(wv_[0]*scale);
      afold_g[64+t]   = (float)(wv_[1]*scale);
      afold_g[128+t]  = (float)(wv_[2]*scale);
      scfold_g[t]     = (float)(bj*scale + bej - mean*scale);
    }
    for (int v = t; v < NVOX; v += 256){
      int key = sm.s2.keys[v];
      unsigned bm = sm.s2.bitmap[key>>5];
      seg[v] = sm.s2.chunkpref[key>>5] + __popc(bm & ((1u << (key&31)) - 1u));
    }
  } else if (b >= 256){
    int rb = (b-256)*16;
    ((float4*)sm.sq.frows)[t]     = ((const float4*)(A + OF_FEAT + (size_t)rb*CD))[t];
    ((float4*)sm.sq.frows)[t+256] = ((const float4*)(A + OF_FEAT + (size_t)rb*CD))[t+256];
    __syncthreads();
    int c = t&127, gp = t>>7;
    const float* wq = A + OF_WQ;
    float bqc = A[OF_BQ+c];
    #pragma unroll
    for (int pass=0; pass<2; ++pass){
      int r0 = pass*8 + gp*4;
      float a0=bqc, a1=bqc, a2=bqc, a3=bqc;
      #pragma unroll 4
      for (int i=0;i<CD;++i){
        float w = wq[i*CD+c];
        a0 += sm.sq.frows[r0+0][i]*w;
        a1 += sm.sq.frows[r0+1][i]*w;
        a2 += sm.sq.frows[r0+2][i]*w;
        a3 += sm.sq.frows[r0+3][i]*w;
      }
      qb[(size_t)(rb+r0+0)*CD+c]=a0; qb[(size_t)(rb+r0+1)*CD+c]=a1;
      qb[(size_t)(rb+r0+2)*CD+c]=a2; qb[(size_t)(rb+r0+3)*CD+c]=a3;
    }
  }
  gbar(bars+1);

  // ================= stage 2: segment softmax-sum + GEMV1 + BN stats (blocks 0-255)
  if (b < 256){
    int w = t>>6, l = t&63;
    float a0 = 0.f, a1 = 0.f;
    for (int k=0;k<4;++k){
      int v = b*16 + w*4 + k;
      float f0 = A[OF_FEAT + (size_t)v*CD + l];
      float f1 = A[OF_FEAT + (size_t)v*CD + 64 + l];
      float m = fmaxf(f0,f1);
      #pragma unroll
      for (int o=32;o;o>>=1) m = fmaxf(m, __shfl_xor(m,o,64));
      float e0 = __expf(f0-m), e1 = __expf(f1-m);
      float ssum = e0+e1;
      #pragma unroll
      for (int o=32;o;o>>=1) ssum += __shfl_xor(ssum,o,64);
      float inv = 1.f/ssum;
      a0 += e0*inv; a1 += e1*inv;
    }
    sm.s34.part[w][l] = a0; sm.s34.part[w][l+64] = a1;
    __syncthreads();
    if (t < CD) sm.s34.row[t] = sm.s34.part[0][t]+sm.s34.part[1][t]+sm.s34.part[2][t]+sm.s34.part[3][t];
    __syncthreads();
    {
      int c = t&127, half = t>>7;
      const float* W = A + OF_CW1;
      float acc = 0.f;
      #pragma unroll 8
      for (int i=half*64; i<half*64+64; ++i) acc += sm.s34.row[i]*W[i*CD+c];
      sm.s34.cpar[half][c] = acc;
    }
    __syncthreads();
    if (t < CD){
      int s = seg[b*16];
      float val = sm.s34.cpar[0][t]+sm.s34.cpar[1][t] + A[OF_CB1+t];
      t1[s*CD+t] = val;
      atomicAdd(&bnsum[t], val);
      atomicAdd(&bnsq[t], val*val);
    }
  }
  gbar(bars+2);

  // ================= stage 3: BN+relu+GEMV2 + k,v projections (blocks 0-255)
  if (b < 256){
    int s = b;
    if (t < CD){
      float mean = bnsum[t]*(1.f/256.f);
      float var  = bnsq[t]*(1.f/256.f) - mean*mean;
      float scv = A[OF_CG1+t]*rsqrtf(var+EPSF);
      float shv = A[OF_CBE1+t] - mean*scv;
      sm.s6.row[t] = fmaxf(t1[(size_t)s*CD+t]*scv + shv, 0.f);
    }
    __syncthreads();
    int c = t&127, half = t>>7;
    {
      const float* W = A + OF_CW2;
      float acc = 0.f;
      #pragma unroll 8
      for (int i=half*64;i<half*64+64;++i) acc += sm.s6.row[i]*W[i*CD+c];
      sm.s6.cpar[half][c] = acc;
    }
    __syncthreads();
    if (t < CD) sm.s6.hrow[t] = sm.s6.cpar[0][t]+sm.s6.cpar[1][t]+A[OF_CB2+t];
    __syncthreads();
    {
      const float* W = half ? (A+OF_WV) : (A+OF_WK);
      float acc = half ? A[OF_BV+c] : A[OF_BK+c];
      #pragma unroll 8
      for (int i=0;i<CD;++i) acc += sm.s6.hrow[i]*W[i*CD+c];
      if (half) vb[(size_t)s*CD+c]=acc; else kb[(size_t)s*CD+c]=acc;
    }
  }
  gbar(bars+3);

  // ================= stage 4: attention (all 512 blocks, 8 queries each)
  {
    int n0 = b*8;
    ((float4*)sm.s9.ubuf)[t] = ((const float4*)(qb + (size_t)n0*CD))[t];
    if (t < 64){
      sm.s9.saf[0][t] = afold_g[t]; sm.s9.saf[1][t] = afold_g[64+t]; sm.s9.saf[2][t] = afold_g[128+t];
      sm.s9.ssc[t] = scfold_g[t]; sm.s9.w2s[t] = A[OF_PW2+t];
    }
    __syncthreads();
    {
      int g = t>>5, j0 = t&31;
      float xv = (float)idx[4*(n0+g)+1];
      float yv = (float)idx[4*(n0+g)+2];
      float zv = (float)idx[4*(n0+g)+3];
      sm.s9.e8T[j0][g]    = sm.s9.saf[0][j0]*xv + sm.s9.saf[1][j0]*yv + sm.s9.saf[2][j0]*zv;
      sm.s9.e8T[j0+32][g] = sm.s9.saf[0][j0+32]*xv + sm.s9.saf[1][j0+32]*yv + sm.s9.saf[2][j0+32]*zv;
    }
    __syncthreads();
    // pbias + scores + exp for supervoxel s = t
    {
      int upk = uxyz[t];
      float uxf = (float)(upk & 255), uyf = (float)((upk>>8)&255), uzf = (float)((upk>>16)&255);
      float pbv[8];
      float pb2v = A[OF_PB2];
      #pragma unroll
      for (int g=0;g<8;++g) pbv[g] = pb2v;
      #pragma unroll 2
      for (int j=0;j<64;++j){
        float dj = sm.s9.ssc[j] - (sm.s9.saf[0][j]*uxf + sm.s9.saf[1][j]*uyf + sm.s9.saf[2][j]*uzf);
        float wj = sm.s9.w2s[j];
        float4 ea = *(const float4*)&sm.s9.e8T[j][0];
        float4 eb = *(const float4*)&sm.s9.e8T[j][4];
        pbv[0] += fmaxf(ea.x+dj,0.f)*wj; pbv[1] += fmaxf(ea.y+dj,0.f)*wj;
        pbv[2] += fmaxf(ea.z+dj,0.f)*wj; pbv[3] += fmaxf(ea.w+dj,0.f)*wj;
        pbv[4] += fmaxf(eb.x+dj,0.f)*wj; pbv[5] += fmaxf(eb.y+dj,0.f)*wj;
        pbv[6] += fmaxf(eb.z+dj,0.f)*wj; pbv[7] += fmaxf(eb.w+dj,0.f)*wj;
      }
      const float4* krow = (const float4*)(kb + (size_t)t*CD);
      for (int h=0;h<HD;++h){
        float4 k0 = krow[h*4+0], k1 = krow[h*4+1], k2 = krow[h*4+2], k3 = krow[h*4+3];
        float p[8];
        #pragma unroll
        for (int g=0;g<8;++g){
          const float* qg = &sm.s9.ubuf[g*CD + h*DHD];
          float dot = qg[0]*k0.x + qg[1]*k0.y + qg[2]*k0.z + qg[3]*k0.w
                    + qg[4]*k1.x + qg[5]*k1.y + qg[6]*k1.z + qg[7]*k1.w
                    + qg[8]*k2.x + qg[9]*k2.y + qg[10]*k2.z + qg[11]*k2.w
                    + qg[12]*k3.x + qg[13]*k3.y + qg[14]*k3.z + qg[15]*k3.w;
          p[g] = __expf(dot*0.25f + pbv[g]);
        }
        sm.s9.sc2[h*4+0][t] = pack2(p[0],p[1]);
        sm.s9.sc2[h*4+1][t] = pack2(p[2],p[3]);
        sm.s9.sc2[h*4+2][t] = pack2(p[4],p[5]);
        sm.s9.sc2[h*4+3][t] = pack2(p[6],p[7]);
      }
    }
    __syncthreads();
    {
      int w = t>>6, lane = t&63;
      for (int h=0;h<HD;++h){
        unsigned ua = sm.s9.sc2[h*4+w][lane];
        unsigned ub = sm.s9.sc2[h*4+w][lane+64];
        unsigned uc = sm.s9.sc2[h*4+w][lane+128];
        unsigned ud = sm.s9.sc2[h*4+w][lane+192];
        float s0 = unlo(ua)+unlo(ub)+unlo(uc)+unlo(ud);
        float s1 = unhi(ua)+unhi(ub)+unhi(uc)+unhi(ud);
        #pragma unroll
        for (int o=32;o;o>>=1){ s0 += __shfl_xor(s0,o,64); s1 += __shfl_xor(s1,o,64); }
        if (lane==0){ sm.s9.rinv[(2*w)*8+h] = 1.f/s0; sm.s9.rinv[(2*w+1)*8+h] = 1.f/s1; }
      }
    }
    __syncthreads();
    // PV
    {
      int half=t>>7, c=t&127, h=c>>4;
      float acc[8]={0.f,0.f,0.f,0.f,0.f,0.f,0.f,0.f};
      for (int s=half*128; s<half*128+128; ++s){
        float v = vb[(size_t)s*CD+c];
        unsigned u0=sm.s9.sc2[h*4+0][s], u1=sm.s9.sc2[h*4+1][s];
        unsigned u2=sm.s9.sc2[h*4+2][s], u3=sm.s9.sc2[h*4+3][s];
        acc[0]+=unlo(u0)*v; acc[1]+=unhi(u0)*v;
        acc[2]+=unlo(u1)*v; acc[3]+=unhi(u1)*v;
        acc[4]+=unlo(u2)*v; acc[5]+=unhi(u2)*v;
        acc[6]+=unlo(u3)*v; acc[7]+=unhi(u3)*v;
      }
      #pragma unroll
      for (int g=0;g<8;++g) sm.s9.cpart[half][g][c]=acc[g];
    }
    __syncthreads();
    // normalize into ctxT, stride 9 (bank-conflict-free)
    {
      int c = t&127;
      for (int g = t>>7; g < 8; g += 2)
        sm.s9.ubuf[c*9+g] = (sm.s9.cpart[0][g][c]+sm.s9.cpart[1][g][c])*sm.s9.rinv[g*8+(c>>4)];
    }
    __syncthreads();
    // wo
    {
      int half=t>>7, c=t&127;
      const float* wo = A + OF_WO;
      float acc[8]={0.f,0.f,0.f,0.f,0.f,0.f,0.f,0.f};
      for (int i=half*64;i<half*64+64;++i){
        float wv = wo[i*CD+c];
        #pragma unroll
        for (int g=0;g<8;++g) acc[g] += sm.s9.ubuf[i*9+g]*wv;
      }
      #pragma unroll
      for (int g=0;g<8;++g) sm.s9.cpart[half][g][c]=acc[g];
    }
    __syncthreads();
    if (t < CD){
      float bov = A[OF_BO+t];
      #pragma unroll
      for (int g=0;g<8;++g)
        sm.s9.ubuf[t*9+g] = sm.s9.cpart[0][g][t]+sm.s9.cpart[1][g][t] + bov
                          + A[OF_FEAT + (size_t)(n0+g)*CD + t];
    }
    __syncthreads();
    // LayerNorm
    {
      int lane = t&63;
      #pragma unroll
      for (int pass=0; pass<2; ++pass){
        int g = (t>>6)*2 + pass;
        float x0 = sm.s9.ubuf[lane*9+g], x1 = sm.s9.ubuf[(lane+64)*9+g];
        float s1 = x0+x1, s2 = x0*x0+x1*x1;
        #pragma unroll
        for (int o=32;o;o>>=1){ s1 += __shfl_xor(s1,o,64); s2 += __shfl_xor(s2,o,64); }
        float mean = s1*(1.f/128.f);
        float var  = s2*(1.f/128.f) - mean*mean;
        float rs = rsqrtf(var + EPSF);
        yb[(size_t)(n0+g)*CD + lane]    = (x0-mean)*rs*A[OF_LNG+lane]    + A[OF_LNB+lane];
        yb[(size_t)(n0+g)*CD + lane+64] = (x1-mean)*rs*A[OF_LNG+lane+64] + A[OF_LNB+lane+64];
      }
    }
  }
  gbar(bars+4);

  // ================= stage 5: SubMConv3d (all 512 blocks, 8 voxels each)
  {
    int p0 = b*8;
    if (t < 32) ((int*)sm.s10.sco4)[t] = idx[4*p0 + t];
    __syncthreads();
    if (t < 216){
      int v = t/27, nb = t - v*27;
      int kd = nb/9, kh = (nb/3)%3, kw = nb%3;
      int bb = sm.s10.sco4[v][0];
      int nx = sm.s10.sco4[v][1]+kd-1, ny = sm.s10.sco4[v][2]+kh-1, nz = sm.s10.sco4[v][3]+kw-1;
      int j = -1;
      if ((unsigned)nx < XD && (unsigned)ny < YD && (unsigned)nz < ZD)
        j = map[((bb*XD+nx)*YD+ny)*ZD+nz];
      sm.s10.jn[v][nb] = j;
    }
    __syncthreads();
    int w = t>>6, l = t&63;
    int og = l & 3, cg = l >> 2;
    int c0 = cg*8;
    float acc[8][5];
    #pragma unroll
    for (int v=0;v<8;++v)
      #pragma unroll
      for (int oo=0;oo<5;++oo) acc[v][oo]=0.f;
    for (int nb = w; nb < 27; nb += 4){
      const float* wbase = wt + (size_t)nb*NCD*CD;
      #pragma unroll
      for (int v=0; v<8; ++v){
        int j = sm.s10.jn[v][nb];
        if (j < 0) continue;
        const float4* y4 = (const float4*)(yb + (size_t)j*CD + c0);
        float4 ya = y4[0], ybb = y4[1];
        #pragma unroll
        for (int oo=0;oo<5;++oo){
          const float4* w4 = (const float4*)(wbase + (size_t)(og*5+oo)*CD + c0);
          float4 wa = w4[0], wb = w4[1];
          acc[v][oo] += ya.x*wa.x + ya.y*wa.y + ya.z*wa.z + ya.w*wa.w
                      + ybb.x*wb.x + ybb.y*wb.y + ybb.z*wb.z + ybb.w*wb.w;
        }
      }
    }
    #pragma unroll
    for (int v=0;v<8;++v)
      #pragma unroll
      for (int oo=0;oo<5;++oo){
        float s = acc[v][oo];
        s += __shfl_xor(s, 4, 64);
        s += __shfl_xor(s, 8, 64);
        s += __shfl_xor(s, 16, 64);
        s += __shfl_xor(s, 32, 64);
        if (cg == 0) sm.s10.partial[w][v][og*5+oo] = s;
      }
    __syncthreads();
    if (t < 160){
      int v = t/20, o = t - v*20;
      float s = sm.s10.partial[0][v][o]+sm.s10.partial[1][v][o]
              + sm.s10.partial[2][v][o]+sm.s10.partial[3][v][o] + A[OF_SEGB+o];
      if (fl) ((ushort_t*)outv)[(size_t)(p0+v)*NCD + o] = f2bf(s);
      else    ((float*)outv)[(size_t)(p0+v)*NCD + o]   = s;
    }
  }
}

// ---------------- launch ----------------
extern "C" void kernel_launch(void* const* d_in, const int* in_sizes, int n_in,
                              void* d_out, int out_size, void* d_ws, size_t ws_size,
                              hipStream_t stream) {
  const int* idx = (const int*)d_in[0];

  char* w = (char*)d_ws;
  size_t off = 0;
  #define ALLOC(name, type, count) \
    type* name = (type*)(w + off); off += (((size_t)(count)*sizeof(type)) + 255) & ~(size_t)255;
  ALLOC(bars,   int,   64)
  ALLOC(arena,  float, ARENA_N)
  ALLOC(wt,     float, 27*NCD*CD)
  ALLOC(map,    int,   MAPN)
  ALLOC(seg,    int,   NVOX)
  ALLOC(afold,  float, 192)
  ALLOC(scfold, float, 64)
  ALLOC(uxyz,   int,   NSV)
  ALLOC(t1,     float, NSV*CD)
  ALLOC(bnsum,  float, CD)
  ALLOC(bnsq,   float, CD)
  ALLOC(kb,     float, NSV*CD)
  ALLOC(vbuf,   float, NSV*CD)
  ALLOC(qb,     float, NVOX*CD)
  ALLOC(yb,     float, NVOX*CD)
  #undef ALLOC
  (void)off; (void)ws_size; (void)n_in; (void)in_sizes; (void)out_size;

  SrcPtrs sp;
  for (int i=0;i<25;++i) sp.p[i] = d_in[i+1];

  kinit <<<1, 64, 0, stream>>>(bars);
  kfused<<<NBLK, 256, 0, stream>>>(sp, idx, bars, arena, wt, map, seg, afold, scfold,
                                   uxyz, t1, bnsum, bnsq, kb, vbuf, qb, yb, d_out);
}

// Round 6
// 255.810 us; speedup vs baseline: 3.2631x; 3.2631x over previous
//
#include <hip/hip_runtime.h>

typedef unsigned short ushort_t;

#define NVOX 4096
#define NSV  256
#define XD   128
#define YD   128
#define ZD   16
#define CD   128
#define NCD  20
#define HD   8
#define DHD  16
#define MAPN 524288
#define EPSF 1e-5f

// ---- fp32 arena offsets (floats) ----
#define OF_FEAT 0
#define OF_CW1  524288
#define OF_CB1  540672
#define OF_CG1  540800
#define OF_CBE1 540928
#define OF_CW2  541056
#define OF_CB2  557440
#define OF_PW1  557568
#define OF_PB1  557760
#define OF_PG1  557824
#define OF_PBE1 557888
#define OF_PW2  557952
#define OF_PB2  558016
#define OF_WQ   558080
#define OF_BQ   574464
#define OF_WK   574592
#define OF_BK   590976
#define OF_WV   591104
#define OF_BV   607488
#define OF_WO   607616
#define OF_BO   624000
#define OF_LNG  624128
#define OF_LNB  624256
#define OF_SEGW 624384
#define OF_SEGB 693504
#define ARENA_N 693568
#define TOTCVT  624341   /* segw excluded (transposed separately) */

__device__ __forceinline__ float bf2f(const ushort_t* p){
  return __uint_as_float(((unsigned)(*p)) << 16);
}
__device__ __forceinline__ ushort_t f2bf(float f){
  unsigned u = __float_as_uint(f);
  u += 0x7fffu + ((u >> 16) & 1u);
  return (ushort_t)(u >> 16);
}
__device__ __forceinline__ unsigned pack2(float a, float b){
  return (unsigned)f2bf(a) | ((unsigned)f2bf(b) << 16);
}
__device__ __forceinline__ float unlo(unsigned u){ return __uint_as_float(u << 16); }
__device__ __forceinline__ float unhi(unsigned u){ return __uint_as_float(u & 0xffff0000u); }

struct SrcPtrs { const void* p[25]; };

__device__ const int g_cnt[25] = {524288,16384,128,128,128,16384,128,192,64,64,64,64,1,
                                  16384,128,16384,128,16384,128,16384,128,128,128,0,20};
__device__ const int g_off[25] = {OF_FEAT,OF_CW1,OF_CB1,OF_CG1,OF_CBE1,OF_CW2,OF_CB2,
                                  OF_PW1,OF_PB1,OF_PG1,OF_PBE1,OF_PW2,OF_PB2,
                                  OF_WQ,OF_BQ,OF_WK,OF_BK,OF_WV,OF_BV,OF_WO,OF_BO,
                                  OF_LNG,OF_LNB,OF_SEGW,OF_SEGB};

__device__ __forceinline__ float ldi(const void* p, int off, int fl){
  return fl ? bf2f((const ushort_t*)p + off) : ((const float*)p)[off];
}

struct S2 { unsigned bitmap[256]; int scnt[256]; int chunkpref[256]; int smom[18]; int keys[NVOX]; };
struct SQ { float frows[16][CD]; };
union __align__(16) UPREP { S2 s2; SQ sq; };

// ========== KPREP: conversion/map-init (b<255) | q-proj (255<=b<=510) | unique (b=511)
__global__ __launch_bounds__(256) void kprep(SrcPtrs sp, const int* idx, int* flag,
    float* arena, float* wt, int* map, int* seg, float* afold_g, float* scfold_g,
    int* uxyz, float* bnsum, float* bnsq, float* qb)
{
  __shared__ UPREP sm;
  __shared__ int sm_flag;
  int t = threadIdx.x, b = blockIdx.x;
  if (t < 64){
    const ushort_t* f16 = (const ushort_t*)sp.p[0];
    unsigned u = f16[2*t];
    int e = (u >> 7) & 0xFF;
    int sane = (u == 0 || (e >= 90 && e <= 150)) ? 1 : 0;
    unsigned long long bl = __ballot(sane);
    if (t == 0) sm_flag = (__popcll(bl) >= 48) ? 1 : 0;
  }
  __syncthreads();
  const int fl = sm_flag;

  if (b < 255){
    // ---- bulk conversion + map init + wt transpose
    int gid = b*256 + t;
    const int GS = 255*256;
    if (gid == 0) *flag = fl;
    for (int k=gid; k<MAPN; k+=GS) map[k] = -1;
    if (gid < CD){ bnsum[gid]=0.f; bnsq[gid]=0.f; }
    for (int el=gid; el<TOTCVT; el+=GS){
      int s=0, rem=el;
      while (rem >= g_cnt[s]){ rem -= g_cnt[s]; ++s; }
      arena[g_off[s]+rem] = ldi(sp.p[s], rem, fl);
    }
    for (int k=gid; k<27*NCD*CD; k+=GS){
      int nb = k/(NCD*CD); int rem = k - nb*(NCD*CD); int o = rem/CD, i = rem - o*CD;
      wt[k] = ldi(sp.p[23], nb*(CD*NCD) + i*NCD + o, fl);
    }
  } else if (b <= 510){
    // ---- q projection for rows rb..rb+15, raw input reads
    int rb = (b-255)*16;
    if (fl){
      const uint4* fsrc = (const uint4*)((const ushort_t*)sp.p[0] + (size_t)rb*CD);
      uint4 u = fsrc[t];
      float* dst = &sm.sq.frows[t>>4][(t&15)*8];
      dst[0]=unlo(u.x); dst[1]=unhi(u.x); dst[2]=unlo(u.y); dst[3]=unhi(u.y);
      dst[4]=unlo(u.z); dst[5]=unhi(u.z); dst[6]=unlo(u.w); dst[7]=unhi(u.w);
    } else {
      const float4* fsrc = (const float4*)((const float*)sp.p[0] + (size_t)rb*CD);
      ((float4*)sm.sq.frows)[t]     = fsrc[t];
      ((float4*)sm.sq.frows)[t+256] = fsrc[t+256];
    }
    __syncthreads();
    int c = t&127, gp = t>>7;
    float bqc = ldi(sp.p[14], c, fl);
    #pragma unroll
    for (int pass=0; pass<2; ++pass){
      int r0 = pass*8 + gp*4;
      float a0=bqc, a1=bqc, a2=bqc, a3=bqc;
      if (fl){
        const ushort_t* wqp = (const ushort_t*)sp.p[13];
        #pragma unroll 4
        for (int i=0;i<CD;++i){
          float w = bf2f(wqp + i*CD + c);
          a0 += sm.sq.frows[r0+0][i]*w;
          a1 += sm.sq.frows[r0+1][i]*w;
          a2 += sm.sq.frows[r0+2][i]*w;
          a3 += sm.sq.frows[r0+3][i]*w;
        }
      } else {
        const float* wqp = (const float*)sp.p[13];
        #pragma unroll 4
        for (int i=0;i<CD;++i){
          float w = wqp[i*CD + c];
          a0 += sm.sq.frows[r0+0][i]*w;
          a1 += sm.sq.frows[r0+1][i]*w;
          a2 += sm.sq.frows[r0+2][i]*w;
          a3 += sm.sq.frows[r0+3][i]*w;
        }
      }
      qb[(size_t)(rb+r0+0)*CD+c]=a0; qb[(size_t)(rb+r0+1)*CD+c]=a1;
      qb[(size_t)(rb+r0+2)*CD+c]=a2; qb[(size_t)(rb+r0+3)*CD+c]=a3;
    }
  } else {
    // ---- b == 511: unique ranks + closed-form BN fold (raw input reads, no map writes)
    sm.s2.bitmap[t] = 0;
    if (t < 18) sm.s2.smom[t] = 0;
    __syncthreads();
    int sacc[9] = {0,0,0,0,0,0,0,0,0};
    for (int v = t; v < NVOX; v += 256){
      int4 q = ((const int4*)idx)[v];
      int key = q.x*4096 + (q.y>>2)*128 + (q.z>>2)*4 + (q.w>>2);
      sm.s2.keys[v] = key;
      atomicOr(&sm.s2.bitmap[key>>5], 1u << (key&31));
      sacc[0]+=q.y; sacc[1]+=q.z; sacc[2]+=q.w;
      sacc[3]+=q.y*q.y; sacc[4]+=q.z*q.z; sacc[5]+=q.w*q.w;
      sacc[6]+=q.y*q.z; sacc[7]+=q.y*q.w; sacc[8]+=q.z*q.w;
    }
    for (int i=0;i<9;++i) atomicAdd(&sm.s2.smom[9+i], sacc[i]);
    __syncthreads();
    int cnt = __popc(sm.s2.bitmap[t]);
    sm.s2.scnt[t] = cnt;
    __syncthreads();
    for (int off=1; off<256; off<<=1){
      int v = (t >= off) ? sm.s2.scnt[t-off] : 0;
      __syncthreads();
      sm.s2.scnt[t] += v;
      __syncthreads();
    }
    int r = sm.s2.scnt[t] - cnt;
    sm.s2.chunkpref[t] = r;
    int um[9] = {0,0,0,0,0,0,0,0,0};
    {
      unsigned bits = sm.s2.bitmap[t];
      while (bits){
        int bpos = __ffs(bits) - 1;
        bits &= bits - 1;
        int key = t*32 + bpos;
        int gx=(key>>7)&31, gy=(key>>2)&31, gz=key&3;
        uxyz[r] = gx | (gy<<8) | (gz<<16);
        um[0]+=gx; um[1]+=gy; um[2]+=gz;
        um[3]+=gx*gx; um[4]+=gy*gy; um[5]+=gz*gz;
        um[6]+=gx*gy; um[7]+=gx*gz; um[8]+=gy*gz;
        ++r;
      }
    }
    for (int i=0;i<9;++i) atomicAdd(&sm.s2.smom[i], um[i]);
    __syncthreads();
    if (t < 64){
      int* smom = sm.s2.smom;
      double U1[3]={(double)smom[0],(double)smom[1],(double)smom[2]};
      double S1[3]={(double)smom[9],(double)smom[10],(double)smom[11]};
      double Uxx[3][3], Sxx[3][3];
      Uxx[0][0]=smom[3]; Uxx[1][1]=smom[4]; Uxx[2][2]=smom[5];
      Uxx[0][1]=Uxx[1][0]=smom[6]; Uxx[0][2]=Uxx[2][0]=smom[7]; Uxx[1][2]=Uxx[2][1]=smom[8];
      Sxx[0][0]=smom[12]; Sxx[1][1]=smom[13]; Sxx[2][2]=smom[14];
      Sxx[0][1]=Sxx[1][0]=smom[15]; Sxx[0][2]=Sxx[2][0]=smom[16]; Sxx[1][2]=Sxx[2][1]=smom[17];
      double M1[3], M2[3][3];
      for (int a=0;a<3;++a) M1[a] = 256.0*S1[a] - 4096.0*U1[a];
      for (int a=0;a<3;++a)
        for (int b2=0;b2<3;++b2)
          M2[a][b2] = 256.0*Sxx[a][b2] - S1[a]*U1[b2] - S1[b2]*U1[a] + 4096.0*Uxx[a][b2];
      double wv_[3]={(double)ldi(sp.p[7],t,fl),(double)ldi(sp.p[7],64+t,fl),(double)ldi(sp.p[7],128+t,fl)};
      double bj=(double)ldi(sp.p[8],t,fl), gj=(double)ldi(sp.p[9],t,fl), bej=(double)ldi(sp.p[10],t,fl);
      double Mw=0.0, wMw=0.0;
      for (int a=0;a<3;++a){
        Mw += M1[a]*wv_[a];
        for (int b2=0;b2<3;++b2) wMw += wv_[a]*M2[a][b2]*wv_[b2];
      }
      const double NM = 1048576.0;
      double mean = Mw/NM + bj;
      double Ey2  = wMw/NM + 2.0*bj*Mw/NM + bj*bj;
      double var  = Ey2 - mean*mean;
      double scale = gj / sqrt(var + 1e-5);
      afold_g[t]      = (float)(wv_[0]*scale);
      afold_g[64+t]   = (float)(wv_[1]*scale);
      afold_g[128+t]  = (float)(wv_[2]*scale);
      scfold_g[t]     = (float)(bj*scale + bej - mean*scale);
    }
    for (int v = t; v < NVOX; v += 256){
      int key = sm.s2.keys[v];
      unsigned bm = sm.s2.bitmap[key>>5];
      seg[v] = sm.s2.chunkpref[key>>5] + __popc(bm & ((1u << (key&31)) - 1u));
    }
  }
}

// ========== K34: map scatter + segment softmax-sum + GEMV1 + BN stats
__global__ __launch_bounds__(256) void k34(const float* A, const int* idx, const int* seg,
                                           int* map, float* t1, float* bnsum, float* bnsq){
  __shared__ float part[4][CD];
  __shared__ float row[CD];
  __shared__ float cpar[2][CD];
  int t = threadIdx.x;
  int b = blockIdx.x;
  if (t < 16){
    int4 q = ((const int4*)idx)[b*16 + t];
    map[((q.x*XD + q.y)*YD + q.z)*ZD + q.w] = b*16 + t;
  }
  int w = t>>6, l = t&63;
  float a0 = 0.f, a1 = 0.f;
  for (int k=0;k<4;++k){
    int v = b*16 + w*4 + k;
    float f0 = A[OF_FEAT + (size_t)v*CD + l];
    float f1 = A[OF_FEAT + (size_t)v*CD + 64 + l];
    float m = fmaxf(f0,f1);
    #pragma unroll
    for (int o=32;o;o>>=1) m = fmaxf(m, __shfl_xor(m,o,64));
    float e0 = __expf(f0-m), e1 = __expf(f1-m);
    float ssum = e0+e1;
    #pragma unroll
    for (int o=32;o;o>>=1) ssum += __shfl_xor(ssum,o,64);
    float inv = 1.f/ssum;
    a0 += e0*inv; a1 += e1*inv;
  }
  part[w][l] = a0; part[w][l+64] = a1;
  __syncthreads();
  if (t < CD) row[t] = part[0][t]+part[1][t]+part[2][t]+part[3][t];
  __syncthreads();
  {
    int c = t&127, half = t>>7;
    const float* W = A + OF_CW1;
    float acc = 0.f;
    #pragma unroll 8
    for (int i=half*64; i<half*64+64; ++i) acc += row[i]*W[i*CD+c];
    cpar[half][c] = acc;
  }
  __syncthreads();
  if (t < CD){
    int s = seg[b*16];
    float val = cpar[0][t]+cpar[1][t] + A[OF_CB1+t];
    t1[s*CD+t] = val;
    atomicAdd(&bnsum[t], val);
    atomicAdd(&bnsq[t], val*val);
  }
}

// ========== K6: BN + relu + GEMV2 + k,v projections
__global__ __launch_bounds__(256) void k6_fused(const float* t1, const float* A,
    const float* bnsum, const float* bnsq, float* kb, float* vb){
  __shared__ float row[CD];
  __shared__ float cpar[2][CD];
  __shared__ float hrow[CD];
  int t = threadIdx.x, s = blockIdx.x;
  if (t < CD){
    float mean = bnsum[t]*(1.f/256.f);
    float var  = bnsq[t]*(1.f/256.f) - mean*mean;
    float scv = A[OF_CG1+t]*rsqrtf(var+EPSF);
    float shv = A[OF_CBE1+t] - mean*scv;
    row[t] = fmaxf(t1[(size_t)s*CD+t]*scv + shv, 0.f);
  }
  __syncthreads();
  int c = t&127, half = t>>7;
  {
    const float* W = A + OF_CW2;
    float acc = 0.f;
    #pragma unroll 8
    for (int i=half*64;i<half*64+64;++i) acc += row[i]*W[i*CD+c];
    cpar[half][c] = acc;
  }
  __syncthreads();
  if (t < CD) hrow[t] = cpar[0][t]+cpar[1][t]+A[OF_CB2+t];
  __syncthreads();
  {
    const float* W = half ? (A+OF_WV) : (A+OF_WK);
    float acc = half ? A[OF_BV+c] : A[OF_BK+c];
    #pragma unroll 8
    for (int i=0;i<CD;++i) acc += hrow[i]*W[i*CD+c];
    if (half) vb[(size_t)s*CD+c]=acc; else kb[(size_t)s*CD+c]=acc;
  }
}

// ========== K9: pbias + attention + wo + residual + LN (8 queries/block)
__global__ __launch_bounds__(256) void k9_attn(
    const float* A, const int* idx, const float* afold_g, const float* scfold_g,
    const int* uxyz, const float* kb, const float* vb, const float* qb, float* yb)
{
  __shared__ __align__(16) float ubuf[1152];   // q [g*128+c] (ph A) / ctxT stride-9 (ph B)
  __shared__ __align__(16) unsigned sc2[NSV][36]; // probs row-major, uint4 per (s,h)
  __shared__ __align__(16) float e8T[64][8];
  __shared__ float saf[3][64];
  __shared__ float ssc[64];
  __shared__ float w2s[64];
  __shared__ float cpart[2][8][CD];
  __shared__ float rinv[64];
  int t = threadIdx.x;
  int n0 = blockIdx.x*8;
  ((float4*)ubuf)[t] = ((const float4*)(qb + (size_t)n0*CD))[t];
  if (t < 64){
    saf[0][t] = afold_g[t]; saf[1][t] = afold_g[64+t]; saf[2][t] = afold_g[128+t];
    ssc[t] = scfold_g[t]; w2s[t] = A[OF_PW2+t];
  }
  __syncthreads();
  {
    int g = t>>5, j0 = t&31;
    float xv = (float)idx[4*(n0+g)+1];
    float yv = (float)idx[4*(n0+g)+2];
    float zv = (float)idx[4*(n0+g)+3];
    e8T[j0][g]    = saf[0][j0]*xv + saf[1][j0]*yv + saf[2][j0]*zv;
    e8T[j0+32][g] = saf[0][j0+32]*xv + saf[1][j0+32]*yv + saf[2][j0+32]*zv;
  }
  __syncthreads();
  // pbias + scores + exp for supervoxel s = t
  {
    int upk = uxyz[t];
    float uxf = (float)(upk & 255), uyf = (float)((upk>>8)&255), uzf = (float)((upk>>16)&255);
    float pbv[8];
    float pb2v = A[OF_PB2];
    #pragma unroll
    for (int g=0;g<8;++g) pbv[g] = pb2v;
    #pragma unroll 2
    for (int j=0;j<64;++j){
      float dj = ssc[j] - (saf[0][j]*uxf + saf[1][j]*uyf + saf[2][j]*uzf);
      float wj = w2s[j];
      float4 ea = *(const float4*)&e8T[j][0];
      float4 eb = *(const float4*)&e8T[j][4];
      pbv[0] += fmaxf(ea.x+dj,0.f)*wj; pbv[1] += fmaxf(ea.y+dj,0.f)*wj;
      pbv[2] += fmaxf(ea.z+dj,0.f)*wj; pbv[3] += fmaxf(ea.w+dj,0.f)*wj;
      pbv[4] += fmaxf(eb.x+dj,0.f)*wj; pbv[5] += fmaxf(eb.y+dj,0.f)*wj;
      pbv[6] += fmaxf(eb.z+dj,0.f)*wj; pbv[7] += fmaxf(eb.w+dj,0.f)*wj;
    }
    const float4* krow = (const float4*)(kb + (size_t)t*CD);
    for (int h=0;h<HD;++h){
      float4 k0 = krow[h*4+0], k1 = krow[h*4+1], k2 = krow[h*4+2], k3 = krow[h*4+3];
      float p[8];
      #pragma unroll
      for (int g=0;g<8;++g){
        const float* qg = &ubuf[g*CD + h*DHD];
        float dot = qg[0]*k0.x + qg[1]*k0.y + qg[2]*k0.z + qg[3]*k0.w
                  + qg[4]*k1.x + qg[5]*k1.y + qg[6]*k1.z + qg[7]*k1.w
                  + qg[8]*k2.x + qg[9]*k2.y + qg[10]*k2.z + qg[11]*k2.w
                  + qg[12]*k3.x + qg[13]*k3.y + qg[14]*k3.z + qg[15]*k3.w;
        p[g] = __expf(dot*0.25f + pbv[g]);
      }
      uint4 pk;
      pk.x = pack2(p[0],p[1]); pk.y = pack2(p[2],p[3]);
      pk.z = pack2(p[4],p[5]); pk.w = pack2(p[6],p[7]);
      *(uint4*)&sc2[t][h*4] = pk;
    }
  }
  __syncthreads();
  // denominators: wave w handles q = 2w, 2w+1
  {
    int w = t>>6, lane = t&63;
    for (int h=0;h<HD;++h){
      unsigned ua = sc2[lane][h*4+w];
      unsigned ub = sc2[lane+64][h*4+w];
      unsigned uc = sc2[lane+128][h*4+w];
      unsigned ud = sc2[lane+192][h*4+w];
      float s0 = unlo(ua)+unlo(ub)+unlo(uc)+unlo(ud);
      float s1 = unhi(ua)+unhi(ub)+unhi(uc)+unhi(ud);
      #pragma unroll
      for (int o=32;o;o>>=1){ s0 += __shfl_xor(s0,o,64); s1 += __shfl_xor(s1,o,64); }
      if (lane==0){ rinv[(2*w)*8+h] = 1.f/s0; rinv[(2*w+1)*8+h] = 1.f/s1; }
    }
  }
  __syncthreads();
  // PV: one b128 broadcast read per iteration
  {
    int half=t>>7, c=t&127, h=c>>4;
    float acc[8]={0.f,0.f,0.f,0.f,0.f,0.f,0.f,0.f};
    for (int s=half*128; s<half*128+128; ++s){
      float v = vb[(size_t)s*CD+c];
      uint4 u4 = *(const uint4*)&sc2[s][h*4];
      acc[0]+=unlo(u4.x)*v; acc[1]+=unhi(u4.x)*v;
      acc[2]+=unlo(u4.y)*v; acc[3]+=unhi(u4.y)*v;
      acc[4]+=unlo(u4.z)*v; acc[5]+=unhi(u4.z)*v;
      acc[6]+=unlo(u4.w)*v; acc[7]+=unhi(u4.w)*v;
    }
    #pragma unroll
    for (int g=0;g<8;++g) cpart[half][g][c]=acc[g];
  }
  __syncthreads();
  // normalize into ctxT, stride 9 (bank-conflict-free)
  {
    int c = t&127;
    for (int g = t>>7; g < 8; g += 2)
      ubuf[c*9+g] = (cpart[0][g][c]+cpart[1][g][c])*rinv[g*8+(c>>4)];
  }
  __syncthreads();
  // wo
  {
    int half=t>>7, c=t&127;
    const float* wo = A + OF_WO;
    float acc[8]={0.f,0.f,0.f,0.f,0.f,0.f,0.f,0.f};
    for (int i=half*64;i<half*64+64;++i){
      float wv = wo[i*CD+c];
      #pragma unroll
      for (int g=0;g<8;++g) acc[g] += ubuf[i*9+g]*wv;
    }
    #pragma unroll
    for (int g=0;g<8;++g) cpart[half][g][c]=acc[g];
  }
  __syncthreads();
  if (t < CD){
    float bov = A[OF_BO+t];
    #pragma unroll
    for (int g=0;g<8;++g)
      ubuf[t*9+g] = cpart[0][g][t]+cpart[1][g][t] + bov
                  + A[OF_FEAT + (size_t)(n0+g)*CD + t];
  }
  __syncthreads();
  // LayerNorm
  {
    int lane = t&63;
    #pragma unroll
    for (int pass=0; pass<2; ++pass){
      int g = (t>>6)*2 + pass;
      float x0 = ubuf[lane*9+g], x1 = ubuf[(lane+64)*9+g];
      float s1 = x0+x1, s2 = x0*x0+x1*x1;
      #pragma unroll
      for (int o=32;o;o>>=1){ s1 += __shfl_xor(s1,o,64); s2 += __shfl_xor(s2,o,64); }
      float mean = s1*(1.f/128.f);
      float var  = s2*(1.f/128.f) - mean*mean;
      float rs = rsqrtf(var + EPSF);
      yb[(size_t)(n0+g)*CD + lane]    = (x0-mean)*rs*A[OF_LNG+lane]    + A[OF_LNB+lane];
      yb[(size_t)(n0+g)*CD + lane+64] = (x1-mean)*rs*A[OF_LNG+lane+64] + A[OF_LNB+lane+64];
    }
  }
}

// ========== K10: SubMConv3d, 8 voxels/block, weights hoisted out of voxel loop
__global__ __launch_bounds__(256) void k10_conv(const int* idx, const int* map,
    const float* yb, const float* A, const float* wt, const int* flag, void* outv)
{
  __shared__ int sco4[8][4];
  __shared__ int jn[8][27];
  __shared__ float partial[4][8][NCD];
  int t = threadIdx.x;
  int p0 = blockIdx.x*8;
  if (t < 32) ((int*)sco4)[t] = idx[4*p0 + t];
  __syncthreads();
  if (t < 216){
    int v = t/27, nb = t - v*27;
    int kd = nb/9, kh = (nb/3)%3, kw = nb%3;
    int bb = sco4[v][0];
    int nx = sco4[v][1]+kd-1, ny = sco4[v][2]+kh-1, nz = sco4[v][3]+kw-1;
    int j = -1;
    if ((unsigned)nx < XD && (unsigned)ny < YD && (unsigned)nz < ZD)
      j = map[((bb*XD+nx)*YD+ny)*ZD+nz];
    jn[v][nb] = j;
  }
  __syncthreads();
  int w = t>>6, l = t&63;
  int og = l & 3, cg = l >> 2;
  int c0 = cg*8;
  float acc[8][5];
  #pragma unroll
  for (int v=0;v<8;++v)
    #pragma unroll
    for (int oo=0;oo<5;++oo) acc[v][oo]=0.f;
  for (int nb = w; nb < 27; nb += 4){
    const float* wbase = wt + (size_t)nb*NCD*CD + c0;
    float4 wreg[10];
    #pragma unroll
    for (int oo=0;oo<5;++oo){
      wreg[oo*2]   = *(const float4*)(wbase + (size_t)(og*5+oo)*CD);
      wreg[oo*2+1] = *(const float4*)(wbase + (size_t)(og*5+oo)*CD + 4);
    }
    #pragma unroll
    for (int v=0; v<8; ++v){
      int j = jn[v][nb];
      if (j < 0) continue;
      const float4* y4 = (const float4*)(yb + (size_t)j*CD + c0);
      float4 ya = y4[0], ybb = y4[1];
      #pragma unroll
      for (int oo=0;oo<5;++oo){
        float4 wa = wreg[oo*2], wb = wreg[oo*2+1];
        acc[v][oo] += ya.x*wa.x + ya.y*wa.y + ya.z*wa.z + ya.w*wa.w
                    + ybb.x*wb.x + ybb.y*wb.y + ybb.z*wb.z + ybb.w*wb.w;
      }
    }
  }
  #pragma unroll
  for (int v=0;v<8;++v)
    #pragma unroll
    for (int oo=0;oo<5;++oo){
      float s = acc[v][oo];
      s += __shfl_xor(s, 4, 64);
      s += __shfl_xor(s, 8, 64);
      s += __shfl_xor(s, 16, 64);
      s += __shfl_xor(s, 32, 64);
      if (cg == 0) partial[w][v][og*5+oo] = s;
    }
  __syncthreads();
  if (t < 160){
    int v = t/20, o = t - v*20;
    float s = partial[0][v][o]+partial[1][v][o]+partial[2][v][o]+partial[3][v][o]
            + A[OF_SEGB+o];
    if (*flag) ((ushort_t*)outv)[(size_t)(p0+v)*NCD + o] = f2bf(s);
    else       ((float*)outv)[(size_t)(p0+v)*NCD + o]   = s;
  }
}

// ---------------- launch ----------------
extern "C" void kernel_launch(void* const* d_in, const int* in_sizes, int n_in,
                              void* d_out, int out_size, void* d_ws, size_t ws_size,
                              hipStream_t stream) {
  const int* idx = (const int*)d_in[0];

  char* w = (char*)d_ws;
  size_t off = 0;
  #define ALLOC(name, type, count) \
    type* name = (type*)(w + off); off += (((size_t)(count)*sizeof(type)) + 255) & ~(size_t)255;
  ALLOC(flag,   int,   64)
  ALLOC(arena,  float, ARENA_N)
  ALLOC(wt,     float, 27*NCD*CD)
  ALLOC(map,    int,   MAPN)
  ALLOC(seg,    int,   NVOX)
  ALLOC(afold,  float, 192)
  ALLOC(scfold, float, 64)
  ALLOC(uxyz,   int,   NSV)
  ALLOC(t1,     float, NSV*CD)
  ALLOC(bnsum,  float, CD)
  ALLOC(bnsq,   float, CD)
  ALLOC(kb,     float, NSV*CD)
  ALLOC(vbuf,   float, NSV*CD)
  ALLOC(qb,     float, NVOX*CD)
  ALLOC(yb,     float, NVOX*CD)
  #undef ALLOC
  (void)off; (void)ws_size; (void)n_in; (void)in_sizes; (void)out_size;

  SrcPtrs sp;
  for (int i=0;i<25;++i) sp.p[i] = d_in[i+1];

  kprep   <<<512, 256, 0, stream>>>(sp, idx, flag, arena, wt, map, seg, afold, scfold,
                                    uxyz, bnsum, bnsq, qb);
  k34     <<<NSV, 256, 0, stream>>>(arena, idx, seg, map, t1, bnsum, bnsq);
  k6_fused<<<NSV, 256, 0, stream>>>(t1, arena, bnsum, bnsq, kb, vbuf);
  k9_attn <<<NVOX/8, 256, 0, stream>>>(arena, idx, afold, scfold, uxyz, kb, vbuf, qb, yb);
  k10_conv<<<NVOX/8, 256, 0, stream>>>(idx, map, yb, arena, wt, flag, d_out);
}

// Round 7
// 249.626 us; speedup vs baseline: 3.3440x; 1.0248x over previous
//
#include <hip/hip_runtime.h>

typedef unsigned short ushort_t;

#define NVOX 4096
#define NSV  256
#define XD   128
#define YD   128
#define ZD   16
#define CD   128
#define NCD  20
#define HD   8
#define DHD  16
#define MAPN 524288
#define EPSF 1e-5f

// ---- fp32 arena offsets (floats) ----
#define OF_FEAT 0
#define OF_CW1  524288
#define OF_CB1  540672
#define OF_CG1  540800
#define OF_CBE1 540928
#define OF_CW2  541056
#define OF_CB2  557440
#define OF_PW1  557568
#define OF_PB1  557760
#define OF_PG1  557824
#define OF_PBE1 557888
#define OF_PW2  557952
#define OF_PB2  558016
#define OF_WQ   558080
#define OF_BQ   574464
#define OF_WK   574592
#define OF_BK   590976
#define OF_WV   591104
#define OF_BV   607488
#define OF_WO   607616
#define OF_BO   624000
#define OF_LNG  624128
#define OF_LNB  624256
#define OF_SEGW 624384
#define OF_SEGB 693504
#define ARENA_N 693568
#define TOTCVT  624341   /* segw excluded (transposed separately) */

__device__ __forceinline__ float bf2f(const ushort_t* p){
  return __uint_as_float(((unsigned)(*p)) << 16);
}
__device__ __forceinline__ ushort_t f2bf(float f){
  unsigned u = __float_as_uint(f);
  u += 0x7fffu + ((u >> 16) & 1u);
  return (ushort_t)(u >> 16);
}
__device__ __forceinline__ unsigned pack2(float a, float b){
  return (unsigned)f2bf(a) | ((unsigned)f2bf(b) << 16);
}
__device__ __forceinline__ float unlo(unsigned u){ return __uint_as_float(u << 16); }
__device__ __forceinline__ float unhi(unsigned u){ return __uint_as_float(u & 0xffff0000u); }

struct SrcPtrs { const void* p[25]; };

__device__ const int g_cnt[25] = {524288,16384,128,128,128,16384,128,192,64,64,64,64,1,
                                  16384,128,16384,128,16384,128,16384,128,128,128,0,20};
__device__ const int g_off[25] = {OF_FEAT,OF_CW1,OF_CB1,OF_CG1,OF_CBE1,OF_CW2,OF_CB2,
                                  OF_PW1,OF_PB1,OF_PG1,OF_PBE1,OF_PW2,OF_PB2,
                                  OF_WQ,OF_BQ,OF_WK,OF_BK,OF_WV,OF_BV,OF_WO,OF_BO,
                                  OF_LNG,OF_LNB,OF_SEGW,OF_SEGB};

__device__ __forceinline__ float ldi(const void* p, int off, int fl){
  return fl ? bf2f((const ushort_t*)p + off) : ((const float*)p)[off];
}

struct SV { float frows[16][CD]; float part[4][CD]; float cf[CD]; float cpar[2][CD]; };
struct SM2 { int smom[18]; };
union __align__(16) UPREP { SV sv; SM2 m; };

// ========== KPREP ==========
// b<255: arena conversion + map init + wt transpose
// 255<=b<511: supervoxel sv=b-255: feat->LDS, q-proj, segment softmax-sum, GEMV1 -> t1T
// b==511: integer moments + closed-form BN fold -> afold/scfold
__global__ __launch_bounds__(256) void kprep(SrcPtrs sp, const int* idx, int* flag,
    float* arena, float* wt, int* map, float* afold_g, float* scfold_g,
    float* qb, float* t1T)
{
  __shared__ UPREP sm;
  __shared__ int sm_flag;
  int t = threadIdx.x, b = blockIdx.x;
  if (t < 64){
    const ushort_t* f16 = (const ushort_t*)sp.p[0];
    unsigned u = f16[2*t];
    int e = (u >> 7) & 0xFF;
    int sane = (u == 0 || (e >= 90 && e <= 150)) ? 1 : 0;
    unsigned long long bl = __ballot(sane);
    if (t == 0) sm_flag = (__popcll(bl) >= 48) ? 1 : 0;
  }
  __syncthreads();
  const int fl = sm_flag;

  if (b < 255){
    int gid = b*256 + t;
    const int GS = 255*256;
    if (gid == 0) *flag = fl;
    for (int k=gid; k<MAPN; k+=GS) map[k] = -1;
    for (int el=gid; el<TOTCVT; el+=GS){
      int s=0, rem=el;
      while (rem >= g_cnt[s]){ rem -= g_cnt[s]; ++s; }
      arena[g_off[s]+rem] = ldi(sp.p[s], rem, fl);
    }
    for (int k=gid; k<27*NCD*CD; k+=GS){
      int nb = k/(NCD*CD); int rem = k - nb*(NCD*CD); int o = rem/CD, i = rem - o*CD;
      wt[k] = ldi(sp.p[23], nb*(CD*NCD) + i*NCD + o, fl);
    }
  } else if (b < 511){
    int sv = b - 255;
    int rb = sv*16;
    // ---- load 16 feat rows (raw)
    if (fl){
      const uint4* fsrc = (const uint4*)((const ushort_t*)sp.p[0] + (size_t)rb*CD);
      uint4 u = fsrc[t];
      float* dst = &sm.sv.frows[t>>4][(t&15)*8];
      dst[0]=unlo(u.x); dst[1]=unhi(u.x); dst[2]=unlo(u.y); dst[3]=unhi(u.y);
      dst[4]=unlo(u.z); dst[5]=unhi(u.z); dst[6]=unlo(u.w); dst[7]=unhi(u.w);
    } else {
      const float4* fsrc = (const float4*)((const float*)sp.p[0] + (size_t)rb*CD);
      ((float4*)sm.sv.frows)[t]     = fsrc[t];
      ((float4*)sm.sv.frows)[t+256] = fsrc[t+256];
    }
    __syncthreads();
    // ---- q projection
    {
      int c = t&127, gp = t>>7;
      float bqc = ldi(sp.p[14], c, fl);
      #pragma unroll
      for (int pass=0; pass<2; ++pass){
        int r0 = pass*8 + gp*4;
        float a0=bqc, a1=bqc, a2=bqc, a3=bqc;
        if (fl){
          const ushort_t* wqp = (const ushort_t*)sp.p[13];
          #pragma unroll 4
          for (int i=0;i<CD;++i){
            float w = bf2f(wqp + i*CD + c);
            a0 += sm.sv.frows[r0+0][i]*w;
            a1 += sm.sv.frows[r0+1][i]*w;
            a2 += sm.sv.frows[r0+2][i]*w;
            a3 += sm.sv.frows[r0+3][i]*w;
          }
        } else {
          const float* wqp = (const float*)sp.p[13];
          #pragma unroll 4
          for (int i=0;i<CD;++i){
            float w = wqp[i*CD + c];
            a0 += sm.sv.frows[r0+0][i]*w;
            a1 += sm.sv.frows[r0+1][i]*w;
            a2 += sm.sv.frows[r0+2][i]*w;
            a3 += sm.sv.frows[r0+3][i]*w;
          }
        }
        qb[(size_t)(rb+r0+0)*CD+c]=a0; qb[(size_t)(rb+r0+1)*CD+c]=a1;
        qb[(size_t)(rb+r0+2)*CD+c]=a2; qb[(size_t)(rb+r0+3)*CD+c]=a3;
      }
    }
    // ---- segment softmax-sum (16 rows, 4 per wave)
    {
      int w = t>>6, l = t&63;
      float a0 = 0.f, a1 = 0.f;
      for (int k=0;k<4;++k){
        int r = w*4 + k;
        float f0 = sm.sv.frows[r][l];
        float f1 = sm.sv.frows[r][l+64];
        float m = fmaxf(f0,f1);
        #pragma unroll
        for (int o=32;o;o>>=1) m = fmaxf(m, __shfl_xor(m,o,64));
        float e0 = __expf(f0-m), e1 = __expf(f1-m);
        float ssum = e0+e1;
        #pragma unroll
        for (int o=32;o;o>>=1) ssum += __shfl_xor(ssum,o,64);
        float inv = 1.f/ssum;
        a0 += e0*inv; a1 += e1*inv;
      }
      sm.sv.part[w][l] = a0; sm.sv.part[w][l+64] = a1;
    }
    __syncthreads();
    if (t < CD) sm.sv.cf[t] = sm.sv.part[0][t]+sm.sv.part[1][t]+sm.sv.part[2][t]+sm.sv.part[3][t];
    __syncthreads();
    // ---- GEMV1 (raw cw1)
    {
      int c = t&127, half = t>>7;
      float acc = 0.f;
      if (fl){
        const ushort_t* W = (const ushort_t*)sp.p[1];
        #pragma unroll 8
        for (int i=half*64; i<half*64+64; ++i) acc += sm.sv.cf[i]*bf2f(W + i*CD + c);
      } else {
        const float* W = (const float*)sp.p[1];
        #pragma unroll 8
        for (int i=half*64; i<half*64+64; ++i) acc += sm.sv.cf[i]*W[i*CD+c];
      }
      sm.sv.cpar[half][c] = acc;
    }
    __syncthreads();
    if (t < CD)
      t1T[(size_t)t*NSV + sv] = sm.sv.cpar[0][t]+sm.sv.cpar[1][t] + ldi(sp.p[2], t, fl);
  } else {
    // ---- b == 511: moments + BN fold
    if (t < 18) sm.m.smom[t] = 0;
    __syncthreads();
    int sacc[9] = {0,0,0,0,0,0,0,0,0};
    for (int v = t; v < NVOX; v += 256){
      int4 q = ((const int4*)idx)[v];
      sacc[0]+=q.y; sacc[1]+=q.z; sacc[2]+=q.w;
      sacc[3]+=q.y*q.y; sacc[4]+=q.z*q.z; sacc[5]+=q.w*q.w;
      sacc[6]+=q.y*q.z; sacc[7]+=q.y*q.w; sacc[8]+=q.z*q.w;
    }
    for (int i=0;i<9;++i) atomicAdd(&sm.m.smom[9+i], sacc[i]);
    {
      // supervoxel (cell) moments: one cell per thread (t<256 = all threads)
      int4 q = ((const int4*)idx)[t*16];
      int gx=q.y>>2, gy=q.z>>2, gz=q.w>>2;
      atomicAdd(&sm.m.smom[0], gx); atomicAdd(&sm.m.smom[1], gy); atomicAdd(&sm.m.smom[2], gz);
      atomicAdd(&sm.m.smom[3], gx*gx); atomicAdd(&sm.m.smom[4], gy*gy); atomicAdd(&sm.m.smom[5], gz*gz);
      atomicAdd(&sm.m.smom[6], gx*gy); atomicAdd(&sm.m.smom[7], gx*gz); atomicAdd(&sm.m.smom[8], gy*gz);
    }
    __syncthreads();
    if (t < 64){
      int* smom = sm.m.smom;
      double U1[3]={(double)smom[0],(double)smom[1],(double)smom[2]};
      double S1[3]={(double)smom[9],(double)smom[10],(double)smom[11]};
      double Uxx[3][3], Sxx[3][3];
      Uxx[0][0]=smom[3]; Uxx[1][1]=smom[4]; Uxx[2][2]=smom[5];
      Uxx[0][1]=Uxx[1][0]=smom[6]; Uxx[0][2]=Uxx[2][0]=smom[7]; Uxx[1][2]=Uxx[2][1]=smom[8];
      Sxx[0][0]=smom[12]; Sxx[1][1]=smom[13]; Sxx[2][2]=smom[14];
      Sxx[0][1]=Sxx[1][0]=smom[15]; Sxx[0][2]=Sxx[2][0]=smom[16]; Sxx[1][2]=Sxx[2][1]=smom[17];
      double M1[3], M2[3][3];
      for (int a=0;a<3;++a) M1[a] = 256.0*S1[a] - 4096.0*U1[a];
      for (int a=0;a<3;++a)
        for (int b2=0;b2<3;++b2)
          M2[a][b2] = 256.0*Sxx[a][b2] - S1[a]*U1[b2] - S1[b2]*U1[a] + 4096.0*Uxx[a][b2];
      double wv_[3]={(double)ldi(sp.p[7],t,fl),(double)ldi(sp.p[7],64+t,fl),(double)ldi(sp.p[7],128+t,fl)};
      double bj=(double)ldi(sp.p[8],t,fl), gj=(double)ldi(sp.p[9],t,fl), bej=(double)ldi(sp.p[10],t,fl);
      double Mw=0.0, wMw=0.0;
      for (int a=0;a<3;++a){
        Mw += M1[a]*wv_[a];
        for (int b2=0;b2<3;++b2) wMw += wv_[a]*M2[a][b2]*wv_[b2];
      }
      const double NM = 1048576.0;
      double mean = Mw/NM + bj;
      double Ey2  = wMw/NM + 2.0*bj*Mw/NM + bj*bj;
      double var  = Ey2 - mean*mean;
      double scale = gj / sqrt(var + 1e-5);
      afold_g[t]      = (float)(wv_[0]*scale);
      afold_g[64+t]   = (float)(wv_[1]*scale);
      afold_g[128+t]  = (float)(wv_[2]*scale);
      scfold_g[t]     = (float)(bj*scale + bej - mean*scale);
    }
  }
}

// ========== K6: map scatter + BN stats from t1T + BN+relu+GEMV2 + k,v proj ==========
__global__ __launch_bounds__(256) void k6_fused(const float* t1T, const float* A,
    const int* idx, int* map, float* kb, float* vb){
  __shared__ float row[CD];
  __shared__ float cpar[2][CD];
  __shared__ float hrow[CD];
  int t = threadIdx.x, s = blockIdx.x;
  if (t >= 128 && t < 144){
    int v = s*16 + (t-128);
    int4 q = ((const int4*)idx)[v];
    map[((q.x*XD + q.y)*YD + q.z)*ZD + q.w] = v;
  }
  if (t < CD){
    const float4* col = (const float4*)(t1T + (size_t)t*NSV);
    float sum=0.f, sq=0.f;
    #pragma unroll 8
    for (int i=0;i<NSV/4;++i){
      float4 v = col[i];
      sum += v.x+v.y+v.z+v.w;
      sq  += v.x*v.x+v.y*v.y+v.z*v.z+v.w*v.w;
    }
    float mean = sum*(1.f/256.f);
    float var  = sq*(1.f/256.f) - mean*mean;
    float scv = A[OF_CG1+t]*rsqrtf(var+EPSF);
    float shv = A[OF_CBE1+t] - mean*scv;
    row[t] = fmaxf(t1T[(size_t)t*NSV + s]*scv + shv, 0.f);
  }
  __syncthreads();
  int c = t&127, half = t>>7;
  {
    const float* W = A + OF_CW2;
    float acc = 0.f;
    #pragma unroll 8
    for (int i=half*64;i<half*64+64;++i) acc += row[i]*W[i*CD+c];
    cpar[half][c] = acc;
  }
  __syncthreads();
  if (t < CD) hrow[t] = cpar[0][t]+cpar[1][t]+A[OF_CB2+t];
  __syncthreads();
  {
    const float* W = half ? (A+OF_WV) : (A+OF_WK);
    float acc = half ? A[OF_BV+c] : A[OF_BK+c];
    #pragma unroll 8
    for (int i=0;i<CD;++i) acc += hrow[i]*W[i*CD+c];
    if (half) vb[(size_t)s*CD+c]=acc; else kb[(size_t)s*CD+c]=acc;
  }
}

// ========== K9: pbias + attention + wo + residual + LN (4 queries/block, 1024 blocks)
__global__ __launch_bounds__(256) void k9_attn(
    const float* A, const int* idx, const float* afold_g, const float* scfold_g,
    const float* kb, const float* vb, const float* qb, float* yb)
{
  __shared__ __align__(16) float q4s[4][CD];       // 2 KB
  __shared__ __align__(16) unsigned sc2[NSV][20];  // 20 KB probs, row-major, uint2/(s,h)
  __shared__ __align__(16) float ctxT[CD*4];       // 2 KB
  __shared__ float cpart[2][4][CD];                // 4 KB
  __shared__ __align__(16) float e4T[64][4];       // 1 KB
  __shared__ float saf[3][64];
  __shared__ float ssc[64];
  __shared__ float w2s[64];
  __shared__ float rinv[32];
  int t = threadIdx.x;
  int n0 = blockIdx.x*4;
  if (t < 128) ((float4*)q4s)[t] = ((const float4*)(qb + (size_t)n0*CD))[t];
  if (t < 64){
    saf[0][t] = afold_g[t]; saf[1][t] = afold_g[64+t]; saf[2][t] = afold_g[128+t];
    ssc[t] = scfold_g[t]; w2s[t] = A[OF_PW2+t];
  }
  __syncthreads();
  {
    int g = t>>6, j = t&63;
    float xv = (float)idx[4*(n0+g)+1];
    float yv = (float)idx[4*(n0+g)+2];
    float zv = (float)idx[4*(n0+g)+3];
    e4T[j][g] = saf[0][j]*xv + saf[1][j]*yv + saf[2][j]*zv;
  }
  __syncthreads();
  // pbias + scores + exp for supervoxel s = t (coords inline from idx)
  {
    int4 q0 = ((const int4*)idx)[t*16];
    float uxf = (float)(q0.y>>2), uyf = (float)(q0.z>>2), uzf = (float)(q0.w>>2);
    float pbv[4];
    float pb2v = A[OF_PB2];
    #pragma unroll
    for (int g=0;g<4;++g) pbv[g] = pb2v;
    #pragma unroll 2
    for (int j=0;j<64;++j){
      float dj = ssc[j] - (saf[0][j]*uxf + saf[1][j]*uyf + saf[2][j]*uzf);
      float wj = w2s[j];
      float4 ea = *(const float4*)&e4T[j][0];
      pbv[0] += fmaxf(ea.x+dj,0.f)*wj; pbv[1] += fmaxf(ea.y+dj,0.f)*wj;
      pbv[2] += fmaxf(ea.z+dj,0.f)*wj; pbv[3] += fmaxf(ea.w+dj,0.f)*wj;
    }
    const float4* krow = (const float4*)(kb + (size_t)t*CD);
    for (int h=0;h<HD;++h){
      float4 k0 = krow[h*4+0], k1 = krow[h*4+1], k2 = krow[h*4+2], k3 = krow[h*4+3];
      float p[4];
      #pragma unroll
      for (int g=0;g<4;++g){
        const float* qg = &q4s[g][h*DHD];
        float dot = qg[0]*k0.x + qg[1]*k0.y + qg[2]*k0.z + qg[3]*k0.w
                  + qg[4]*k1.x + qg[5]*k1.y + qg[6]*k1.z + qg[7]*k1.w
                  + qg[8]*k2.x + qg[9]*k2.y + qg[10]*k2.z + qg[11]*k2.w
                  + qg[12]*k3.x + qg[13]*k3.y + qg[14]*k3.z + qg[15]*k3.w;
        p[g] = __expf(dot*0.25f + pbv[g]);
      }
      sc2[t][h*2]   = pack2(p[0],p[1]);
      sc2[t][h*2+1] = pack2(p[2],p[3]);
    }
  }
  __syncthreads();
  // denominators: wave g handles query g, all 8 heads
  {
    int g = t>>6, lane = t&63;
    int sel = g&1;
    for (int h=0;h<HD;++h){
      int col = h*2 + (g>>1);
      unsigned ua = sc2[lane][col];
      unsigned ub = sc2[lane+64][col];
      unsigned uc = sc2[lane+128][col];
      unsigned ud = sc2[lane+192][col];
      float s0 = sel ? (unhi(ua)+unhi(ub)+unhi(uc)+unhi(ud))
                     : (unlo(ua)+unlo(ub)+unlo(uc)+unlo(ud));
      #pragma unroll
      for (int o=32;o;o>>=1) s0 += __shfl_xor(s0,o,64);
      if (lane==0) rinv[g*8+h] = 1.f/s0;
    }
  }
  __syncthreads();
  // PV
  {
    int half=t>>7, c=t&127, h=c>>4;
    float acc[4]={0.f,0.f,0.f,0.f};
    for (int s=half*128; s<half*128+128; ++s){
      float v = vb[(size_t)s*CD+c];
      uint2 u2 = *(const uint2*)&sc2[s][h*2];
      acc[0]+=unlo(u2.x)*v; acc[1]+=unhi(u2.x)*v;
      acc[2]+=unlo(u2.y)*v; acc[3]+=unhi(u2.y)*v;
    }
    #pragma unroll
    for (int g=0;g<4;++g) cpart[half][g][c]=acc[g];
  }
  __syncthreads();
  if (t < CD){
    int h = t>>4;
    #pragma unroll
    for (int g=0;g<4;++g)
      ctxT[t*4+g] = (cpart[0][g][t]+cpart[1][g][t])*rinv[g*8+h];
  }
  __syncthreads();
  // wo
  {
    int half=t>>7, c=t&127;
    const float* wo = A + OF_WO;
    float acc[4]={0.f,0.f,0.f,0.f};
    for (int i=half*64;i<half*64+64;++i){
      float wv = wo[i*CD+c];
      float4 r = *(const float4*)&ctxT[i*4];
      acc[0]+=r.x*wv; acc[1]+=r.y*wv; acc[2]+=r.z*wv; acc[3]+=r.w*wv;
    }
    #pragma unroll
    for (int g=0;g<4;++g) cpart[half][g][c]=acc[g];
  }
  __syncthreads();
  if (t < CD){
    float bov = A[OF_BO+t];
    #pragma unroll
    for (int g=0;g<4;++g)
      ctxT[t*4+g] = cpart[0][g][t]+cpart[1][g][t] + bov
                  + A[OF_FEAT + (size_t)(n0+g)*CD + t];
  }
  __syncthreads();
  // LayerNorm: wave g handles row g
  {
    int g = t>>6, lane = t&63;
    float x0 = ctxT[lane*4+g], x1 = ctxT[(lane+64)*4+g];
    float s1 = x0+x1, s2 = x0*x0+x1*x1;
    #pragma unroll
    for (int o=32;o;o>>=1){ s1 += __shfl_xor(s1,o,64); s2 += __shfl_xor(s2,o,64); }
    float mean = s1*(1.f/128.f);
    float var  = s2*(1.f/128.f) - mean*mean;
    float rs = rsqrtf(var + EPSF);
    yb[(size_t)(n0+g)*CD + lane]    = (x0-mean)*rs*A[OF_LNG+lane]    + A[OF_LNB+lane];
    yb[(size_t)(n0+g)*CD + lane+64] = (x1-mean)*rs*A[OF_LNG+lane+64] + A[OF_LNB+lane+64];
  }
}

// ========== K10: SubMConv3d, 8 voxels/block, weights hoisted ==========
__global__ __launch_bounds__(256) void k10_conv(const int* idx, const int* map,
    const float* yb, const float* A, const float* wt, const int* flag, void* outv)
{
  __shared__ int sco4[8][4];
  __shared__ int jn[8][27];
  __shared__ float partial[4][8][NCD];
  int t = threadIdx.x;
  int p0 = blockIdx.x*8;
  if (t < 32) ((int*)sco4)[t] = idx[4*p0 + t];
  __syncthreads();
  if (t < 216){
    int v = t/27, nb = t - v*27;
    int kd = nb/9, kh = (nb/3)%3, kw = nb%3;
    int bb = sco4[v][0];
    int nx = sco4[v][1]+kd-1, ny = sco4[v][2]+kh-1, nz = sco4[v][3]+kw-1;
    int j = -1;
    if ((unsigned)nx < XD && (unsigned)ny < YD && (unsigned)nz < ZD)
      j = map[((bb*XD+nx)*YD+ny)*ZD+nz];
    jn[v][nb] = j;
  }
  __syncthreads();
  int w = t>>6, l = t&63;
  int og = l & 3, cg = l >> 2;
  int c0 = cg*8;
  float acc[8][5];
  #pragma unroll
  for (int v=0;v<8;++v)
    #pragma unroll
    for (int oo=0;oo<5;++oo) acc[v][oo]=0.f;
  for (int nb = w; nb < 27; nb += 4){
    const float* wbase = wt + (size_t)nb*NCD*CD + c0;
    float4 wreg[10];
    #pragma unroll
    for (int oo=0;oo<5;++oo){
      wreg[oo*2]   = *(const float4*)(wbase + (size_t)(og*5+oo)*CD);
      wreg[oo*2+1] = *(const float4*)(wbase + (size_t)(og*5+oo)*CD + 4);
    }
    #pragma unroll
    for (int v=0; v<8; ++v){
      int j = jn[v][nb];
      if (j < 0) continue;
      const float4* y4 = (const float4*)(yb + (size_t)j*CD + c0);
      float4 ya = y4[0], ybb = y4[1];
      #pragma unroll
      for (int oo=0;oo<5;++oo){
        float4 wa = wreg[oo*2], wb = wreg[oo*2+1];
        acc[v][oo] += ya.x*wa.x + ya.y*wa.y + ya.z*wa.z + ya.w*wa.w
                    + ybb.x*wb.x + ybb.y*wb.y + ybb.z*wb.z + ybb.w*wb.w;
      }
    }
  }
  #pragma unroll
  for (int v=0;v<8;++v)
    #pragma unroll
    for (int oo=0;oo<5;++oo){
      float s = acc[v][oo];
      s += __shfl_xor(s, 4, 64);
      s += __shfl_xor(s, 8, 64);
      s += __shfl_xor(s, 16, 64);
      s += __shfl_xor(s, 32, 64);
      if (cg == 0) partial[w][v][og*5+oo] = s;
    }
  __syncthreads();
  if (t < 160){
    int v = t/20, o = t - v*20;
    float s = partial[0][v][o]+partial[1][v][o]+partial[2][v][o]+partial[3][v][o]
            + A[OF_SEGB+o];
    if (*flag) ((ushort_t*)outv)[(size_t)(p0+v)*NCD + o] = f2bf(s);
    else       ((float*)outv)[(size_t)(p0+v)*NCD + o]   = s;
  }
}

// ---------------- launch ----------------
extern "C" void kernel_launch(void* const* d_in, const int* in_sizes, int n_in,
                              void* d_out, int out_size, void* d_ws, size_t ws_size,
                              hipStream_t stream) {
  const int* idx = (const int*)d_in[0];

  char* w = (char*)d_ws;
  size_t off = 0;
  #define ALLOC(name, type, count) \
    type* name = (type*)(w + off); off += (((size_t)(count)*sizeof(type)) + 255) & ~(size_t)255;
  ALLOC(flag,   int,   64)
  ALLOC(arena,  float, ARENA_N)
  ALLOC(wt,     float, 27*NCD*CD)
  ALLOC(map,    int,   MAPN)
  ALLOC(afold,  float, 192)
  ALLOC(scfold, float, 64)
  ALLOC(t1T,    float, CD*NSV)
  ALLOC(kb,     float, NSV*CD)
  ALLOC(vbuf,   float, NSV*CD)
  ALLOC(qb,     float, NVOX*CD)
  ALLOC(yb,     float, NVOX*CD)
  #undef ALLOC
  (void)off; (void)ws_size; (void)n_in; (void)in_sizes; (void)out_size;

  SrcPtrs sp;
  for (int i=0;i<25;++i) sp.p[i] = d_in[i+1];

  kprep   <<<512, 256, 0, stream>>>(sp, idx, flag, arena, wt, map, afold, scfold, qb, t1T);
  k6_fused<<<NSV, 256, 0, stream>>>(t1T, arena, idx, map, kb, vbuf);
  k9_attn <<<NVOX/4, 256, 0, stream>>>(arena, idx, afold, scfold, kb, vbuf, qb, yb);
  k10_conv<<<NVOX/8, 256, 0, stream>>>(idx, map, yb, arena, wt, flag, d_out);
}

// Round 8
// 247.500 us; speedup vs baseline: 3.3727x; 1.0086x over previous
//
#include <hip/hip_runtime.h>

typedef unsigned short ushort_t;

#define NVOX 4096
#define NSV  256
#define XD   128
#define YD   128
#define ZD   16
#define CD   128
#define NCD  20
#define HD   8
#define DHD  16
#define MAPN 524288
#define EPSF 1e-5f

// ---- fp32 arena offsets (floats) ----
#define OF_FEAT 0
#define OF_CW1  524288
#define OF_CB1  540672
#define OF_CG1  540800
#define OF_CBE1 540928
#define OF_CW2  541056
#define OF_CB2  557440
#define OF_PW1  557568
#define OF_PB1  557760
#define OF_PG1  557824
#define OF_PBE1 557888
#define OF_PW2  557952
#define OF_PB2  558016
#define OF_WQ   558080
#define OF_BQ   574464
#define OF_WK   574592
#define OF_BK   590976
#define OF_WV   591104
#define OF_BV   607488
#define OF_WO   607616
#define OF_BO   624000
#define OF_LNG  624128
#define OF_LNB  624256
#define OF_SEGW 624384
#define OF_SEGB 693504
#define ARENA_N 693568
#define TOTCVT  624341   /* segw excluded (transposed separately) */

__device__ __forceinline__ float bf2f(const ushort_t* p){
  return __uint_as_float(((unsigned)(*p)) << 16);
}
__device__ __forceinline__ ushort_t f2bf(float f){
  unsigned u = __float_as_uint(f);
  u += 0x7fffu + ((u >> 16) & 1u);
  return (ushort_t)(u >> 16);
}
__device__ __forceinline__ unsigned pack2(float a, float b){
  return (unsigned)f2bf(a) | ((unsigned)f2bf(b) << 16);
}
__device__ __forceinline__ float unlo(unsigned u){ return __uint_as_float(u << 16); }
__device__ __forceinline__ float unhi(unsigned u){ return __uint_as_float(u & 0xffff0000u); }

struct SrcPtrs { const void* p[25]; };

__device__ const int g_cnt[25] = {524288,16384,128,128,128,16384,128,192,64,64,64,64,1,
                                  16384,128,16384,128,16384,128,16384,128,128,128,0,20};
__device__ const int g_off[25] = {OF_FEAT,OF_CW1,OF_CB1,OF_CG1,OF_CBE1,OF_CW2,OF_CB2,
                                  OF_PW1,OF_PB1,OF_PG1,OF_PBE1,OF_PW2,OF_PB2,
                                  OF_WQ,OF_BQ,OF_WK,OF_BK,OF_WV,OF_BV,OF_WO,OF_BO,
                                  OF_LNG,OF_LNB,OF_SEGW,OF_SEGB};

__device__ __forceinline__ float ldi(const void* p, int off, int fl){
  return fl ? bf2f((const ushort_t*)p + off) : ((const float*)p)[off];
}

struct SV { float frows[16][CD]; float part[4][CD]; float cf[CD]; float cpar[2][CD]; };
struct SM2 { int smom[18]; };
union __align__(16) UPREP { SV sv; SM2 m; };

// ========== KPREP ==========
// b<255: arena conversion + map init + wt transpose
// 255<=b<511: supervoxel sv=b-255: feat->LDS, q-proj, segment softmax-sum, GEMV1 -> t1T
// b==511: integer moments + closed-form BN fold -> afold/scfold
__global__ __launch_bounds__(256) void kprep(SrcPtrs sp, const int* idx, int* flag,
    float* arena, float* wt, int* map, float* afold_g, float* scfold_g,
    float* qb, float* t1T)
{
  __shared__ UPREP sm;
  __shared__ int sm_flag;
  int t = threadIdx.x, b = blockIdx.x;
  if (t < 64){
    const ushort_t* f16 = (const ushort_t*)sp.p[0];
    unsigned u = f16[2*t];
    int e = (u >> 7) & 0xFF;
    int sane = (u == 0 || (e >= 90 && e <= 150)) ? 1 : 0;
    unsigned long long bl = __ballot(sane);
    if (t == 0) sm_flag = (__popcll(bl) >= 48) ? 1 : 0;
  }
  __syncthreads();
  const int fl = sm_flag;

  if (b < 255){
    int gid = b*256 + t;
    const int GS = 255*256;
    if (gid == 0) *flag = fl;
    for (int k=gid; k<MAPN; k+=GS) map[k] = -1;
    for (int el=gid; el<TOTCVT; el+=GS){
      int s=0, rem=el;
      while (rem >= g_cnt[s]){ rem -= g_cnt[s]; ++s; }
      arena[g_off[s]+rem] = ldi(sp.p[s], rem, fl);
    }
    for (int k=gid; k<27*NCD*CD; k+=GS){
      int nb = k/(NCD*CD); int rem = k - nb*(NCD*CD); int o = rem/CD, i = rem - o*CD;
      wt[k] = ldi(sp.p[23], nb*(CD*NCD) + i*NCD + o, fl);
    }
  } else if (b < 511){
    int sv = b - 255;
    int rb = sv*16;
    // ---- load 16 feat rows (raw)
    if (fl){
      const uint4* fsrc = (const uint4*)((const ushort_t*)sp.p[0] + (size_t)rb*CD);
      uint4 u = fsrc[t];
      float* dst = &sm.sv.frows[t>>4][(t&15)*8];
      dst[0]=unlo(u.x); dst[1]=unhi(u.x); dst[2]=unlo(u.y); dst[3]=unhi(u.y);
      dst[4]=unlo(u.z); dst[5]=unhi(u.z); dst[6]=unlo(u.w); dst[7]=unhi(u.w);
    } else {
      const float4* fsrc = (const float4*)((const float*)sp.p[0] + (size_t)rb*CD);
      ((float4*)sm.sv.frows)[t]     = fsrc[t];
      ((float4*)sm.sv.frows)[t+256] = fsrc[t+256];
    }
    __syncthreads();
    // ---- q projection
    {
      int c = t&127, gp = t>>7;
      float bqc = ldi(sp.p[14], c, fl);
      #pragma unroll
      for (int pass=0; pass<2; ++pass){
        int r0 = pass*8 + gp*4;
        float a0=bqc, a1=bqc, a2=bqc, a3=bqc;
        if (fl){
          const ushort_t* wqp = (const ushort_t*)sp.p[13];
          #pragma unroll 4
          for (int i=0;i<CD;++i){
            float w = bf2f(wqp + i*CD + c);
            a0 += sm.sv.frows[r0+0][i]*w;
            a1 += sm.sv.frows[r0+1][i]*w;
            a2 += sm.sv.frows[r0+2][i]*w;
            a3 += sm.sv.frows[r0+3][i]*w;
          }
        } else {
          const float* wqp = (const float*)sp.p[13];
          #pragma unroll 4
          for (int i=0;i<CD;++i){
            float w = wqp[i*CD + c];
            a0 += sm.sv.frows[r0+0][i]*w;
            a1 += sm.sv.frows[r0+1][i]*w;
            a2 += sm.sv.frows[r0+2][i]*w;
            a3 += sm.sv.frows[r0+3][i]*w;
          }
        }
        qb[(size_t)(rb+r0+0)*CD+c]=a0; qb[(size_t)(rb+r0+1)*CD+c]=a1;
        qb[(size_t)(rb+r0+2)*CD+c]=a2; qb[(size_t)(rb+r0+3)*CD+c]=a3;
      }
    }
    // ---- segment softmax-sum (16 rows, 4 per wave)
    {
      int w = t>>6, l = t&63;
      float a0 = 0.f, a1 = 0.f;
      for (int k=0;k<4;++k){
        int r = w*4 + k;
        float f0 = sm.sv.frows[r][l];
        float f1 = sm.sv.frows[r][l+64];
        float m = fmaxf(f0,f1);
        #pragma unroll
        for (int o=32;o;o>>=1) m = fmaxf(m, __shfl_xor(m,o,64));
        float e0 = __expf(f0-m), e1 = __expf(f1-m);
        float ssum = e0+e1;
        #pragma unroll
        for (int o=32;o;o>>=1) ssum += __shfl_xor(ssum,o,64);
        float inv = 1.f/ssum;
        a0 += e0*inv; a1 += e1*inv;
      }
      sm.sv.part[w][l] = a0; sm.sv.part[w][l+64] = a1;
    }
    __syncthreads();
    if (t < CD) sm.sv.cf[t] = sm.sv.part[0][t]+sm.sv.part[1][t]+sm.sv.part[2][t]+sm.sv.part[3][t];
    __syncthreads();
    // ---- GEMV1 (raw cw1)
    {
      int c = t&127, half = t>>7;
      float acc = 0.f;
      if (fl){
        const ushort_t* W = (const ushort_t*)sp.p[1];
        #pragma unroll 8
        for (int i=half*64; i<half*64+64; ++i) acc += sm.sv.cf[i]*bf2f(W + i*CD + c);
      } else {
        const float* W = (const float*)sp.p[1];
        #pragma unroll 8
        for (int i=half*64; i<half*64+64; ++i) acc += sm.sv.cf[i]*W[i*CD+c];
      }
      sm.sv.cpar[half][c] = acc;
    }
    __syncthreads();
    if (t < CD)
      t1T[(size_t)t*NSV + sv] = sm.sv.cpar[0][t]+sm.sv.cpar[1][t] + ldi(sp.p[2], t, fl);
  } else {
    // ---- b == 511: moments + BN fold
    if (t < 18) sm.m.smom[t] = 0;
    __syncthreads();
    int sacc[9] = {0,0,0,0,0,0,0,0,0};
    for (int v = t; v < NVOX; v += 256){
      int4 q = ((const int4*)idx)[v];
      sacc[0]+=q.y; sacc[1]+=q.z; sacc[2]+=q.w;
      sacc[3]+=q.y*q.y; sacc[4]+=q.z*q.z; sacc[5]+=q.w*q.w;
      sacc[6]+=q.y*q.z; sacc[7]+=q.y*q.w; sacc[8]+=q.z*q.w;
    }
    for (int i=0;i<9;++i) atomicAdd(&sm.m.smom[9+i], sacc[i]);
    {
      int4 q = ((const int4*)idx)[t*16];
      int gx=q.y>>2, gy=q.z>>2, gz=q.w>>2;
      atomicAdd(&sm.m.smom[0], gx); atomicAdd(&sm.m.smom[1], gy); atomicAdd(&sm.m.smom[2], gz);
      atomicAdd(&sm.m.smom[3], gx*gx); atomicAdd(&sm.m.smom[4], gy*gy); atomicAdd(&sm.m.smom[5], gz*gz);
      atomicAdd(&sm.m.smom[6], gx*gy); atomicAdd(&sm.m.smom[7], gx*gz); atomicAdd(&sm.m.smom[8], gy*gz);
    }
    __syncthreads();
    if (t < 64){
      int* smom = sm.m.smom;
      double U1[3]={(double)smom[0],(double)smom[1],(double)smom[2]};
      double S1[3]={(double)smom[9],(double)smom[10],(double)smom[11]};
      double Uxx[3][3], Sxx[3][3];
      Uxx[0][0]=smom[3]; Uxx[1][1]=smom[4]; Uxx[2][2]=smom[5];
      Uxx[0][1]=Uxx[1][0]=smom[6]; Uxx[0][2]=Uxx[2][0]=smom[7]; Uxx[1][2]=Uxx[2][1]=smom[8];
      Sxx[0][0]=smom[12]; Sxx[1][1]=smom[13]; Sxx[2][2]=smom[14];
      Sxx[0][1]=Sxx[1][0]=smom[15]; Sxx[0][2]=Sxx[2][0]=smom[16]; Sxx[1][2]=Sxx[2][1]=smom[17];
      double M1[3], M2[3][3];
      for (int a=0;a<3;++a) M1[a] = 256.0*S1[a] - 4096.0*U1[a];
      for (int a=0;a<3;++a)
        for (int b2=0;b2<3;++b2)
          M2[a][b2] = 256.0*Sxx[a][b2] - S1[a]*U1[b2] - S1[b2]*U1[a] + 4096.0*Uxx[a][b2];
      double wv_[3]={(double)ldi(sp.p[7],t,fl),(double)ldi(sp.p[7],64+t,fl),(double)ldi(sp.p[7],128+t,fl)};
      double bj=(double)ldi(sp.p[8],t,fl), gj=(double)ldi(sp.p[9],t,fl), bej=(double)ldi(sp.p[10],t,fl);
      double Mw=0.0, wMw=0.0;
      for (int a=0;a<3;++a){
        Mw += M1[a]*wv_[a];
        for (int b2=0;b2<3;++b2) wMw += wv_[a]*M2[a][b2]*wv_[b2];
      }
      const double NM = 1048576.0;
      double mean = Mw/NM + bj;
      double Ey2  = wMw/NM + 2.0*bj*Mw/NM + bj*bj;
      double var  = Ey2 - mean*mean;
      double scale = gj / sqrt(var + 1e-5);
      afold_g[t]      = (float)(wv_[0]*scale);
      afold_g[64+t]   = (float)(wv_[1]*scale);
      afold_g[128+t]  = (float)(wv_[2]*scale);
      scfold_g[t]     = (float)(bj*scale + bej - mean*scale);
    }
  }
}

// ========== K6: map scatter + BN stats from t1T + BN+relu+GEMV2 + k,v proj ==========
__global__ __launch_bounds__(256) void k6_fused(const float* t1T, const float* A,
    const int* idx, int* map, float* kb, float* vb){
  __shared__ float row[CD];
  __shared__ float cpar[2][CD];
  __shared__ float hrow[CD];
  int t = threadIdx.x, s = blockIdx.x;
  if (t >= 128 && t < 144){
    int v = s*16 + (t-128);
    int4 q = ((const int4*)idx)[v];
    map[((q.x*XD + q.y)*YD + q.z)*ZD + q.w] = v;
  }
  if (t < CD){
    const float4* col = (const float4*)(t1T + (size_t)t*NSV);
    float sum=0.f, sq=0.f;
    #pragma unroll 8
    for (int i=0;i<NSV/4;++i){
      float4 v = col[i];
      sum += v.x+v.y+v.z+v.w;
      sq  += v.x*v.x+v.y*v.y+v.z*v.z+v.w*v.w;
    }
    float mean = sum*(1.f/256.f);
    float var  = sq*(1.f/256.f) - mean*mean;
    float scv = A[OF_CG1+t]*rsqrtf(var+EPSF);
    float shv = A[OF_CBE1+t] - mean*scv;
    row[t] = fmaxf(t1T[(size_t)t*NSV + s]*scv + shv, 0.f);
  }
  __syncthreads();
  int c = t&127, half = t>>7;
  {
    const float* W = A + OF_CW2;
    float acc = 0.f;
    #pragma unroll 8
    for (int i=half*64;i<half*64+64;++i) acc += row[i]*W[i*CD+c];
    cpar[half][c] = acc;
  }
  __syncthreads();
  if (t < CD) hrow[t] = cpar[0][t]+cpar[1][t]+A[OF_CB2+t];
  __syncthreads();
  {
    const float* W = half ? (A+OF_WV) : (A+OF_WK);
    float acc = half ? A[OF_BV+c] : A[OF_BK+c];
    #pragma unroll 8
    for (int i=0;i<CD;++i) acc += hrow[i]*W[i*CD+c];
    if (half) vb[(size_t)s*CD+c]=acc; else kb[(size_t)s*CD+c]=acc;
  }
}

// ========== K9: pbias + attention + wo + residual + LN (4 queries/block, ILP-forced)
__global__ __launch_bounds__(256) void k9_attn(
    const float* A, const int* idx, const float* afold_g, const float* scfold_g,
    const float* kb, const float* vb, const float* qb, float* yb)
{
  __shared__ __align__(16) float q4s[4][CD];       // 2 KB
  __shared__ __align__(16) unsigned sc2[NSV][20];  // 20 KB probs, row-major, uint2/(s,h)
  __shared__ __align__(16) float ctxT[CD*4];       // 2 KB
  __shared__ float cpart[2][4][CD];                // 4 KB
  __shared__ __align__(16) float e4T[64][4];       // 1 KB
  __shared__ float saf[3][64];
  __shared__ float ssc[64];
  __shared__ float w2s[64];
  __shared__ float rinv[32];
  int t = threadIdx.x;
  int n0 = blockIdx.x*4;
  if (t < 128) ((float4*)q4s)[t] = ((const float4*)(qb + (size_t)n0*CD))[t];
  if (t < 64){
    saf[0][t] = afold_g[t]; saf[1][t] = afold_g[64+t]; saf[2][t] = afold_g[128+t];
    ssc[t] = scfold_g[t]; w2s[t] = A[OF_PW2+t];
  }
  __syncthreads();
  {
    int g = t>>6, j = t&63;
    float xv = (float)idx[4*(n0+g)+1];
    float yv = (float)idx[4*(n0+g)+2];
    float zv = (float)idx[4*(n0+g)+3];
    e4T[j][g] = saf[0][j]*xv + saf[1][j]*yv + saf[2][j]*zv;
  }
  __syncthreads();
  // pbias + scores + exp for supervoxel s = t (coords inline from idx)
  {
    int4 q0 = ((const int4*)idx)[t*16];
    float uxf = (float)(q0.y>>2), uyf = (float)(q0.z>>2), uzf = (float)(q0.w>>2);
    float pbv[4];
    float pb2v = A[OF_PB2];
    #pragma unroll
    for (int g=0;g<4;++g) pbv[g] = pb2v;
    #pragma unroll 2
    for (int j=0;j<64;++j){
      float dj = ssc[j] - (saf[0][j]*uxf + saf[1][j]*uyf + saf[2][j]*uzf);
      float wj = w2s[j];
      float4 ea = *(const float4*)&e4T[j][0];
      pbv[0] += fmaxf(ea.x+dj,0.f)*wj; pbv[1] += fmaxf(ea.y+dj,0.f)*wj;
      pbv[2] += fmaxf(ea.z+dj,0.f)*wj; pbv[3] += fmaxf(ea.w+dj,0.f)*wj;
    }
    const float4* krow = (const float4*)(kb + (size_t)t*CD);
    float4 kc0 = krow[0], kc1 = krow[1], kc2 = krow[2], kc3 = krow[3];
    for (int h=0;h<HD;++h){
      int hn = (h+1)&7;
      float4 kn0 = krow[hn*4+0], kn1 = krow[hn*4+1];
      float4 kn2 = krow[hn*4+2], kn3 = krow[hn*4+3];
      float p[4];
      #pragma unroll
      for (int g=0;g<4;++g){
        const float* qg = &q4s[g][h*DHD];
        float dot = qg[0]*kc0.x + qg[1]*kc0.y + qg[2]*kc0.z + qg[3]*kc0.w
                  + qg[4]*kc1.x + qg[5]*kc1.y + qg[6]*kc1.z + qg[7]*kc1.w
                  + qg[8]*kc2.x + qg[9]*kc2.y + qg[10]*kc2.z + qg[11]*kc2.w
                  + qg[12]*kc3.x + qg[13]*kc3.y + qg[14]*kc3.z + qg[15]*kc3.w;
        p[g] = __expf(dot*0.25f + pbv[g]);
      }
      sc2[t][h*2]   = pack2(p[0],p[1]);
      sc2[t][h*2+1] = pack2(p[2],p[3]);
      kc0 = kn0; kc1 = kn1; kc2 = kn2; kc3 = kn3;
    }
  }
  __syncthreads();
  // denominators: wave g handles query g, all 8 heads
  {
    int g = t>>6, lane = t&63;
    int sel = g&1;
    for (int h=0;h<HD;++h){
      int col = h*2 + (g>>1);
      unsigned ua = sc2[lane][col];
      unsigned ub = sc2[lane+64][col];
      unsigned uc = sc2[lane+128][col];
      unsigned ud = sc2[lane+192][col];
      float s0 = sel ? (unhi(ua)+unhi(ub)+unhi(uc)+unhi(ud))
                     : (unlo(ua)+unlo(ub)+unlo(uc)+unlo(ud));
      #pragma unroll
      for (int o=32;o;o>>=1) s0 += __shfl_xor(s0,o,64);
      if (lane==0) rinv[g*8+h] = 1.f/s0;
    }
  }
  __syncthreads();
  // PV: 8-wide manual unroll, 8 coalesced loads in flight
  {
    int half=t>>7, c=t&127, h=c>>4;
    const float* vcol = vb + c;
    float acc[4]={0.f,0.f,0.f,0.f};
    #pragma unroll 2
    for (int s0=half*128; s0<half*128+128; s0+=8){
      float v0=vcol[(s0+0)*CD], v1=vcol[(s0+1)*CD], v2=vcol[(s0+2)*CD], v3=vcol[(s0+3)*CD];
      float v4=vcol[(s0+4)*CD], v5=vcol[(s0+5)*CD], v6=vcol[(s0+6)*CD], v7=vcol[(s0+7)*CD];
      uint2 u0=*(const uint2*)&sc2[s0+0][h*2];
      uint2 u1=*(const uint2*)&sc2[s0+1][h*2];
      uint2 u2=*(const uint2*)&sc2[s0+2][h*2];
      uint2 u3=*(const uint2*)&sc2[s0+3][h*2];
      uint2 u4=*(const uint2*)&sc2[s0+4][h*2];
      uint2 u5=*(const uint2*)&sc2[s0+5][h*2];
      uint2 u6=*(const uint2*)&sc2[s0+6][h*2];
      uint2 u7=*(const uint2*)&sc2[s0+7][h*2];
      acc[0] += unlo(u0.x)*v0 + unlo(u1.x)*v1 + unlo(u2.x)*v2 + unlo(u3.x)*v3
              + unlo(u4.x)*v4 + unlo(u5.x)*v5 + unlo(u6.x)*v6 + unlo(u7.x)*v7;
      acc[1] += unhi(u0.x)*v0 + unhi(u1.x)*v1 + unhi(u2.x)*v2 + unhi(u3.x)*v3
              + unhi(u4.x)*v4 + unhi(u5.x)*v5 + unhi(u6.x)*v6 + unhi(u7.x)*v7;
      acc[2] += unlo(u0.y)*v0 + unlo(u1.y)*v1 + unlo(u2.y)*v2 + unlo(u3.y)*v3
              + unlo(u4.y)*v4 + unlo(u5.y)*v5 + unlo(u6.y)*v6 + unlo(u7.y)*v7;
      acc[3] += unhi(u0.y)*v0 + unhi(u1.y)*v1 + unhi(u2.y)*v2 + unhi(u3.y)*v3
              + unhi(u4.y)*v4 + unhi(u5.y)*v5 + unhi(u6.y)*v6 + unhi(u7.y)*v7;
    }
    #pragma unroll
    for (int g=0;g<4;++g) cpart[half][g][c]=acc[g];
  }
  __syncthreads();
  if (t < CD){
    int h = t>>4;
    #pragma unroll
    for (int g=0;g<4;++g)
      ctxT[t*4+g] = (cpart[0][g][t]+cpart[1][g][t])*rinv[g*8+h];
  }
  __syncthreads();
  // wo
  {
    int half=t>>7, c=t&127;
    const float* wo = A + OF_WO;
    float acc[4]={0.f,0.f,0.f,0.f};
    #pragma unroll 4
    for (int i=half*64;i<half*64+64;++i){
      float wv = wo[i*CD+c];
      float4 r = *(const float4*)&ctxT[i*4];
      acc[0]+=r.x*wv; acc[1]+=r.y*wv; acc[2]+=r.z*wv; acc[3]+=r.w*wv;
    }
    #pragma unroll
    for (int g=0;g<4;++g) cpart[half][g][c]=acc[g];
  }
  __syncthreads();
  if (t < CD){
    float bov = A[OF_BO+t];
    #pragma unroll
    for (int g=0;g<4;++g)
      ctxT[t*4+g] = cpart[0][g][t]+cpart[1][g][t] + bov
                  + A[OF_FEAT + (size_t)(n0+g)*CD + t];
  }
  __syncthreads();
  // LayerNorm: wave g handles row g
  {
    int g = t>>6, lane = t&63;
    float x0 = ctxT[lane*4+g], x1 = ctxT[(lane+64)*4+g];
    float s1 = x0+x1, s2 = x0*x0+x1*x1;
    #pragma unroll
    for (int o=32;o;o>>=1){ s1 += __shfl_xor(s1,o,64); s2 += __shfl_xor(s2,o,64); }
    float mean = s1*(1.f/128.f);
    float var  = s2*(1.f/128.f) - mean*mean;
    float rs = rsqrtf(var + EPSF);
    yb[(size_t)(n0+g)*CD + lane]    = (x0-mean)*rs*A[OF_LNG+lane]    + A[OF_LNB+lane];
    yb[(size_t)(n0+g)*CD + lane+64] = (x1-mean)*rs*A[OF_LNG+lane+64] + A[OF_LNB+lane+64];
  }
}

// ========== K10: SubMConv3d, 4 voxels/block (1024 blocks), weights hoisted ==========
__global__ __launch_bounds__(256) void k10_conv(const int* idx, const int* map,
    const float* yb, const float* A, const float* wt, const int* flag, void* outv)
{
  __shared__ int sco4[4][4];
  __shared__ int jn[4][27];
  __shared__ float partial[4][4][NCD];
  int t = threadIdx.x;
  int p0 = blockIdx.x*4;
  if (t < 16) ((int*)sco4)[t] = idx[4*p0 + t];
  __syncthreads();
  if (t < 108){
    int v = t/27, nb = t - v*27;
    int kd = nb/9, kh = (nb/3)%3, kw = nb%3;
    int bb = sco4[v][0];
    int nx = sco4[v][1]+kd-1, ny = sco4[v][2]+kh-1, nz = sco4[v][3]+kw-1;
    int j = -1;
    if ((unsigned)nx < XD && (unsigned)ny < YD && (unsigned)nz < ZD)
      j = map[((bb*XD+nx)*YD+ny)*ZD+nz];
    jn[v][nb] = j;
  }
  __syncthreads();
  int w = t>>6, l = t&63;
  int og = l & 3, cg = l >> 2;
  int c0 = cg*8;
  float acc[4][5];
  #pragma unroll
  for (int v=0;v<4;++v)
    #pragma unroll
    for (int oo=0;oo<5;++oo) acc[v][oo]=0.f;
  for (int nb = w; nb < 27; nb += 4){
    const float* wbase = wt + (size_t)nb*NCD*CD + c0;
    float4 wreg[10];
    #pragma unroll
    for (int oo=0;oo<5;++oo){
      wreg[oo*2]   = *(const float4*)(wbase + (size_t)(og*5+oo)*CD);
      wreg[oo*2+1] = *(const float4*)(wbase + (size_t)(og*5+oo)*CD + 4);
    }
    #pragma unroll
    for (int v=0; v<4; ++v){
      int j = jn[v][nb];
      if (j < 0) continue;
      const float4* y4 = (const float4*)(yb + (size_t)j*CD + c0);
      float4 ya = y4[0], ybb = y4[1];
      #pragma unroll
      for (int oo=0;oo<5;++oo){
        float4 wa = wreg[oo*2], wb = wreg[oo*2+1];
        acc[v][oo] += ya.x*wa.x + ya.y*wa.y + ya.z*wa.z + ya.w*wa.w
                    + ybb.x*wb.x + ybb.y*wb.y + ybb.z*wb.z + ybb.w*wb.w;
      }
    }
  }
  #pragma unroll
  for (int v=0;v<4;++v)
    #pragma unroll
    for (int oo=0;oo<5;++oo){
      float s = acc[v][oo];
      s += __shfl_xor(s, 4, 64);
      s += __shfl_xor(s, 8, 64);
      s += __shfl_xor(s, 16, 64);
      s += __shfl_xor(s, 32, 64);
      if (cg == 0) partial[w][v][og*5+oo] = s;
    }
  __syncthreads();
  if (t < 80){
    int v = t/20, o = t - v*20;
    float s = partial[0][v][o]+partial[1][v][o]+partial[2][v][o]+partial[3][v][o]
            + A[OF_SEGB+o];
    if (*flag) ((ushort_t*)outv)[(size_t)(p0+v)*NCD + o] = f2bf(s);
    else       ((float*)outv)[(size_t)(p0+v)*NCD + o]   = s;
  }
}

// ---------------- launch ----------------
extern "C" void kernel_launch(void* const* d_in, const int* in_sizes, int n_in,
                              void* d_out, int out_size, void* d_ws, size_t ws_size,
                              hipStream_t stream) {
  const int* idx = (const int*)d_in[0];

  char* w = (char*)d_ws;
  size_t off = 0;
  #define ALLOC(name, type, count) \
    type* name = (type*)(w + off); off += (((size_t)(count)*sizeof(type)) + 255) & ~(size_t)255;
  ALLOC(flag,   int,   64)
  ALLOC(arena,  float, ARENA_N)
  ALLOC(wt,     float, 27*NCD*CD)
  ALLOC(map,    int,   MAPN)
  ALLOC(afold,  float, 192)
  ALLOC(scfold, float, 64)
  ALLOC(t1T,    float, CD*NSV)
  ALLOC(kb,     float, NSV*CD)
  ALLOC(vbuf,   float, NSV*CD)
  ALLOC(qb,     float, NVOX*CD)
  ALLOC(yb,     float, NVOX*CD)
  #undef ALLOC
  (void)off; (void)ws_size; (void)n_in; (void)in_sizes; (void)out_size;

  SrcPtrs sp;
  for (int i=0;i<25;++i) sp.p[i] = d_in[i+1];

  kprep   <<<512, 256, 0, stream>>>(sp, idx, flag, arena, wt, map, afold, scfold, qb, t1T);
  k6_fused<<<NSV, 256, 0, stream>>>(t1T, arena, idx, map, kb, vbuf);
  k9_attn <<<NVOX/4, 256, 0, stream>>>(arena, idx, afold, scfold, kb, vbuf, qb, yb);
  k10_conv<<<NVOX/4, 256, 0, stream>>>(idx, map, yb, arena, wt, flag, d_out);
}

// Round 9
// 236.366 us; speedup vs baseline: 3.5316x; 1.0471x over previous
//
#include <hip/hip_runtime.h>

typedef unsigned short ushort_t;

#define NVOX 4096
#define NSV  256
#define XD   128
#define YD   128
#define ZD   16
#define CD   128
#define NCD  20
#define HD   8
#define DHD  16
#define MAPN 524288
#define EPSF 1e-5f

// ---- fp32 arena offsets (floats) ----
#define OF_FEAT 0
#define OF_CW1  524288
#define OF_CB1  540672
#define OF_CG1  540800
#define OF_CBE1 540928
#define OF_CW2  541056
#define OF_CB2  557440
#define OF_PW1  557568
#define OF_PB1  557760
#define OF_PG1  557824
#define OF_PBE1 557888
#define OF_PW2  557952
#define OF_PB2  558016
#define OF_WQ   558080
#define OF_BQ   574464
#define OF_WK   574592
#define OF_BK   590976
#define OF_WV   591104
#define OF_BV   607488
#define OF_WO   607616
#define OF_BO   624000
#define OF_LNG  624128
#define OF_LNB  624256
#define OF_SEGW 624384
#define OF_SEGB 693504
#define ARENA_N 693568
#define TOTCVT  624341   /* segw excluded (transposed separately) */

__device__ __forceinline__ float bf2f(const ushort_t* p){
  return __uint_as_float(((unsigned)(*p)) << 16);
}
__device__ __forceinline__ ushort_t f2bf(float f){
  unsigned u = __float_as_uint(f);
  u += 0x7fffu + ((u >> 16) & 1u);
  return (ushort_t)(u >> 16);
}
__device__ __forceinline__ unsigned pack2(float a, float b){
  return (unsigned)f2bf(a) | ((unsigned)f2bf(b) << 16);
}
__device__ __forceinline__ float unlo(unsigned u){ return __uint_as_float(u << 16); }
__device__ __forceinline__ float unhi(unsigned u){ return __uint_as_float(u & 0xffff0000u); }

struct SrcPtrs { const void* p[25]; };

__device__ const int g_cnt[25] = {524288,16384,128,128,128,16384,128,192,64,64,64,64,1,
                                  16384,128,16384,128,16384,128,16384,128,128,128,0,20};
__device__ const int g_off[25] = {OF_FEAT,OF_CW1,OF_CB1,OF_CG1,OF_CBE1,OF_CW2,OF_CB2,
                                  OF_PW1,OF_PB1,OF_PG1,OF_PBE1,OF_PW2,OF_PB2,
                                  OF_WQ,OF_BQ,OF_WK,OF_BK,OF_WV,OF_BV,OF_WO,OF_BO,
                                  OF_LNG,OF_LNB,OF_SEGW,OF_SEGB};

__device__ __forceinline__ float ldi(const void* p, int off, int fl){
  return fl ? bf2f((const ushort_t*)p + off) : ((const float*)p)[off];
}

struct SPREP {
  float frows[16][CD];     // 8 KB
  float qpart[2][16][CD];  // 16 KB
  float part[8][CD];       // 4 KB
  float cfs[CD];           // 0.5 KB
  float gpart[8][CD];      // 4 KB
};
union __align__(16) UPREP { SPREP sv; int smom[18]; };

// ========== KPREP (512 threads) ==========
// b<255: arena conversion + map init + wt transpose
// 255<=b<511: supervoxel sv=b-255: feat->LDS, vectorized q-proj + softmax-sum + GEMV1
// b==511: integer moments + closed-form BN fold -> afold/scfold
__global__ __launch_bounds__(512) void kprep(SrcPtrs sp, const int* idx, int* flag,
    float* arena, float* wt, int* map, float* afold_g, float* scfold_g,
    float* qb, float* t1T)
{
  __shared__ UPREP sm;
  __shared__ int sm_flag;
  int t = threadIdx.x, b = blockIdx.x;
  if (t < 64){
    const ushort_t* f16 = (const ushort_t*)sp.p[0];
    unsigned u = f16[2*t];
    int e = (u >> 7) & 0xFF;
    int sane = (u == 0 || (e >= 90 && e <= 150)) ? 1 : 0;
    unsigned long long bl = __ballot(sane);
    if (t == 0) sm_flag = (__popcll(bl) >= 48) ? 1 : 0;
  }
  __syncthreads();
  const int fl = sm_flag;

  if (b < 255){
    int gid = b*512 + t;
    const int GS = 255*512;
    if (gid == 0) *flag = fl;
    for (int k=gid; k<MAPN; k+=GS) map[k] = -1;
    for (int el=gid; el<TOTCVT; el+=GS){
      int s=0, rem=el;
      while (rem >= g_cnt[s]){ rem -= g_cnt[s]; ++s; }
      arena[g_off[s]+rem] = ldi(sp.p[s], rem, fl);
    }
    for (int k=gid; k<27*NCD*CD; k+=GS){
      int nb = k/(NCD*CD); int rem = k - nb*(NCD*CD); int o = rem/CD, i = rem - o*CD;
      wt[k] = ldi(sp.p[23], nb*(CD*NCD) + i*NCD + o, fl);
    }
  } else if (b < 511){
    int sv = b - 255;
    int rb = sv*16;
    // ---- load 16 feat rows (raw input)
    if (fl){
      const uint2* fsrc = (const uint2*)((const ushort_t*)sp.p[0] + (size_t)rb*CD);
      uint2 u = fsrc[t];
      float* dst = &sm.sv.frows[t>>5][(t&31)*4];
      dst[0]=unlo(u.x); dst[1]=unhi(u.x); dst[2]=unlo(u.y); dst[3]=unhi(u.y);
    } else {
      const float4* fsrc = (const float4*)((const float*)sp.p[0] + (size_t)rb*CD);
      ((float4*)sm.sv.frows)[t] = fsrc[t];
    }
    __syncthreads();
    // ---- q-proj: thread = (c8-group:16, row:16, khalf:2); 8 cols/thread, uint4 weights
    {
      int c8 = (t&15)*8, r = (t>>4)&15, kh = t>>8;
      int i0 = kh*64;
      float acc[8] = {0.f,0.f,0.f,0.f,0.f,0.f,0.f,0.f};
      if (fl){
        const ushort_t* wqp = (const ushort_t*)sp.p[13];
        #pragma unroll 4
        for (int i=i0; i<i0+64; ++i){
          uint4 w4 = *(const uint4*)(wqp + (size_t)i*CD + c8);
          float fr = sm.sv.frows[r][i];
          acc[0] += unlo(w4.x)*fr; acc[1] += unhi(w4.x)*fr;
          acc[2] += unlo(w4.y)*fr; acc[3] += unhi(w4.y)*fr;
          acc[4] += unlo(w4.z)*fr; acc[5] += unhi(w4.z)*fr;
          acc[6] += unlo(w4.w)*fr; acc[7] += unhi(w4.w)*fr;
        }
      } else {
        const float* wqp = (const float*)sp.p[13];
        #pragma unroll 4
        for (int i=i0; i<i0+64; ++i){
          float4 wa = *(const float4*)(wqp + (size_t)i*CD + c8);
          float4 wb = *(const float4*)(wqp + (size_t)i*CD + c8 + 4);
          float fr = sm.sv.frows[r][i];
          acc[0]+=wa.x*fr; acc[1]+=wa.y*fr; acc[2]+=wa.z*fr; acc[3]+=wa.w*fr;
          acc[4]+=wb.x*fr; acc[5]+=wb.y*fr; acc[6]+=wb.z*fr; acc[7]+=wb.w*fr;
        }
      }
      #pragma unroll
      for (int j=0;j<8;++j) sm.sv.qpart[kh][r][c8+j] = acc[j];
    }
    __syncthreads();
    // ---- combine + bias -> qb
    for (int e = t; e < 16*CD; e += 512){
      int r = e>>7, c = e&127;
      qb[(size_t)(rb+r)*CD + c] = sm.sv.qpart[0][r][c] + sm.sv.qpart[1][r][c]
                                + ldi(sp.p[14], c, fl);
    }
    // ---- segment softmax-sum: 8 waves x 2 rows
    {
      int w = t>>6, l = t&63;
      float a0 = 0.f, a1 = 0.f;
      #pragma unroll
      for (int k=0;k<2;++k){
        int r = w*2 + k;
        float f0 = sm.sv.frows[r][l];
        float f1 = sm.sv.frows[r][l+64];
        float m = fmaxf(f0,f1);
        #pragma unroll
        for (int o=32;o;o>>=1) m = fmaxf(m, __shfl_xor(m,o,64));
        float e0 = __expf(f0-m), e1 = __expf(f1-m);
        float ssum = e0+e1;
        #pragma unroll
        for (int o=32;o;o>>=1) ssum += __shfl_xor(ssum,o,64);
        float inv = 1.f/ssum;
        a0 += e0*inv; a1 += e1*inv;
      }
      sm.sv.part[w][l] = a0; sm.sv.part[w][l+64] = a1;
    }
    __syncthreads();
    if (t < CD){
      float s = 0.f;
      #pragma unroll
      for (int w=0;w<8;++w) s += sm.sv.part[w][t];
      sm.sv.cfs[t] = s;
    }
    __syncthreads();
    // ---- GEMV1: thread = (c2:64, kg:8); 2 cols/thread, 16 K each
    {
      int c2 = (t&63)*2, kg = t>>6;
      int i0 = kg*16;
      float a0 = 0.f, a1 = 0.f;
      if (fl){
        const ushort_t* W = (const ushort_t*)sp.p[1];
        #pragma unroll 4
        for (int i=i0; i<i0+16; ++i){
          unsigned w = *(const unsigned*)(W + (size_t)i*CD + c2);
          float cfv = sm.sv.cfs[i];
          a0 += unlo(w)*cfv; a1 += unhi(w)*cfv;
        }
      } else {
        const float* W = (const float*)sp.p[1];
        #pragma unroll 4
        for (int i=i0; i<i0+16; ++i){
          float2 w = *(const float2*)(W + (size_t)i*CD + c2);
          float cfv = sm.sv.cfs[i];
          a0 += w.x*cfv; a1 += w.y*cfv;
        }
      }
      sm.sv.gpart[kg][c2] = a0; sm.sv.gpart[kg][c2+1] = a1;
    }
    __syncthreads();
    if (t < CD){
      float s = 0.f;
      #pragma unroll
      for (int kg=0;kg<8;++kg) s += sm.sv.gpart[kg][t];
      t1T[(size_t)t*NSV + sv] = s + ldi(sp.p[2], t, fl);
    }
  } else {
    // ---- b == 511: moments + BN fold
    if (t < 18) sm.smom[t] = 0;
    __syncthreads();
    int sacc[9] = {0,0,0,0,0,0,0,0,0};
    for (int v = t; v < NVOX; v += 512){
      int4 q = ((const int4*)idx)[v];
      sacc[0]+=q.y; sacc[1]+=q.z; sacc[2]+=q.w;
      sacc[3]+=q.y*q.y; sacc[4]+=q.z*q.z; sacc[5]+=q.w*q.w;
      sacc[6]+=q.y*q.z; sacc[7]+=q.y*q.w; sacc[8]+=q.z*q.w;
    }
    for (int i=0;i<9;++i) atomicAdd(&sm.smom[9+i], sacc[i]);
    if (t < 256){
      int4 q = ((const int4*)idx)[t*16];
      int gx=q.y>>2, gy=q.z>>2, gz=q.w>>2;
      atomicAdd(&sm.smom[0], gx); atomicAdd(&sm.smom[1], gy); atomicAdd(&sm.smom[2], gz);
      atomicAdd(&sm.smom[3], gx*gx); atomicAdd(&sm.smom[4], gy*gy); atomicAdd(&sm.smom[5], gz*gz);
      atomicAdd(&sm.smom[6], gx*gy); atomicAdd(&sm.smom[7], gx*gz); atomicAdd(&sm.smom[8], gy*gz);
    }
    __syncthreads();
    if (t < 64){
      int* smom = sm.smom;
      double U1[3]={(double)smom[0],(double)smom[1],(double)smom[2]};
      double S1[3]={(double)smom[9],(double)smom[10],(double)smom[11]};
      double Uxx[3][3], Sxx[3][3];
      Uxx[0][0]=smom[3]; Uxx[1][1]=smom[4]; Uxx[2][2]=smom[5];
      Uxx[0][1]=Uxx[1][0]=smom[6]; Uxx[0][2]=Uxx[2][0]=smom[7]; Uxx[1][2]=Uxx[2][1]=smom[8];
      Sxx[0][0]=smom[12]; Sxx[1][1]=smom[13]; Sxx[2][2]=smom[14];
      Sxx[0][1]=Sxx[1][0]=smom[15]; Sxx[0][2]=Sxx[2][0]=smom[16]; Sxx[1][2]=Sxx[2][1]=smom[17];
      double M1[3], M2[3][3];
      for (int a=0;a<3;++a) M1[a] = 256.0*S1[a] - 4096.0*U1[a];
      for (int a=0;a<3;++a)
        for (int b2=0;b2<3;++b2)
          M2[a][b2] = 256.0*Sxx[a][b2] - S1[a]*U1[b2] - S1[b2]*U1[a] + 4096.0*Uxx[a][b2];
      double wv_[3]={(double)ldi(sp.p[7],t,fl),(double)ldi(sp.p[7],64+t,fl),(double)ldi(sp.p[7],128+t,fl)};
      double bj=(double)ldi(sp.p[8],t,fl), gj=(double)ldi(sp.p[9],t,fl), bej=(double)ldi(sp.p[10],t,fl);
      double Mw=0.0, wMw=0.0;
      for (int a=0;a<3;++a){
        Mw += M1[a]*wv_[a];
        for (int b2=0;b2<3;++b2) wMw += wv_[a]*M2[a][b2]*wv_[b2];
      }
      const double NM = 1048576.0;
      double mean = Mw/NM + bj;
      double Ey2  = wMw/NM + 2.0*bj*Mw/NM + bj*bj;
      double var  = Ey2 - mean*mean;
      double scale = gj / sqrt(var + 1e-5);
      afold_g[t]      = (float)(wv_[0]*scale);
      afold_g[64+t]   = (float)(wv_[1]*scale);
      afold_g[128+t]  = (float)(wv_[2]*scale);
      scfold_g[t]     = (float)(bj*scale + bej - mean*scale);
    }
  }
}

// ========== K6: map scatter + BN stats from t1T + BN+relu+GEMV2 + k,v proj ==========
__global__ __launch_bounds__(256) void k6_fused(const float* t1T, const float* A,
    const int* idx, int* map, float* kb, float* vb){
  __shared__ float row[CD];
  __shared__ float cpar[2][CD];
  __shared__ float hrow[CD];
  int t = threadIdx.x, s = blockIdx.x;
  if (t >= 128 && t < 144){
    int v = s*16 + (t-128);
    int4 q = ((const int4*)idx)[v];
    map[((q.x*XD + q.y)*YD + q.z)*ZD + q.w] = v;
  }
  if (t < CD){
    const float4* col = (const float4*)(t1T + (size_t)t*NSV);
    float sum=0.f, sq=0.f;
    #pragma unroll 8
    for (int i=0;i<NSV/4;++i){
      float4 v = col[i];
      sum += v.x+v.y+v.z+v.w;
      sq  += v.x*v.x+v.y*v.y+v.z*v.z+v.w*v.w;
    }
    float mean = sum*(1.f/256.f);
    float var  = sq*(1.f/256.f) - mean*mean;
    float scv = A[OF_CG1+t]*rsqrtf(var+EPSF);
    float shv = A[OF_CBE1+t] - mean*scv;
    row[t] = fmaxf(t1T[(size_t)t*NSV + s]*scv + shv, 0.f);
  }
  __syncthreads();
  int c = t&127, half = t>>7;
  {
    const float* W = A + OF_CW2;
    float acc = 0.f;
    #pragma unroll 8
    for (int i=half*64;i<half*64+64;++i) acc += row[i]*W[i*CD+c];
    cpar[half][c] = acc;
  }
  __syncthreads();
  if (t < CD) hrow[t] = cpar[0][t]+cpar[1][t]+A[OF_CB2+t];
  __syncthreads();
  {
    const float* W = half ? (A+OF_WV) : (A+OF_WK);
    float acc = half ? A[OF_BV+c] : A[OF_BK+c];
    #pragma unroll 8
    for (int i=0;i<CD;++i) acc += hrow[i]*W[i*CD+c];
    if (half) vb[(size_t)s*CD+c]=acc; else kb[(size_t)s*CD+c]=acc;
  }
}

// ========== K9: pbias + attention + wo + residual + LN (4 queries/block, ILP-forced)
__global__ __launch_bounds__(256) void k9_attn(
    const float* A, const int* idx, const float* afold_g, const float* scfold_g,
    const float* kb, const float* vb, const float* qb, float* yb)
{
  __shared__ __align__(16) float q4s[4][CD];       // 2 KB
  __shared__ __align__(16) unsigned sc2[NSV][20];  // 20 KB probs, row-major, uint2/(s,h)
  __shared__ __align__(16) float ctxT[CD*4];       // 2 KB
  __shared__ float cpart[2][4][CD];                // 4 KB
  __shared__ __align__(16) float e4T[64][4];       // 1 KB
  __shared__ float saf[3][64];
  __shared__ float ssc[64];
  __shared__ float w2s[64];
  __shared__ float rinv[32];
  int t = threadIdx.x;
  int n0 = blockIdx.x*4;
  if (t < 128) ((float4*)q4s)[t] = ((const float4*)(qb + (size_t)n0*CD))[t];
  if (t < 64){
    saf[0][t] = afold_g[t]; saf[1][t] = afold_g[64+t]; saf[2][t] = afold_g[128+t];
    ssc[t] = scfold_g[t]; w2s[t] = A[OF_PW2+t];
  }
  __syncthreads();
  {
    int g = t>>6, j = t&63;
    float xv = (float)idx[4*(n0+g)+1];
    float yv = (float)idx[4*(n0+g)+2];
    float zv = (float)idx[4*(n0+g)+3];
    e4T[j][g] = saf[0][j]*xv + saf[1][j]*yv + saf[2][j]*zv;
  }
  __syncthreads();
  // pbias + scores + exp for supervoxel s = t (coords inline from idx)
  {
    int4 q0 = ((const int4*)idx)[t*16];
    float uxf = (float)(q0.y>>2), uyf = (float)(q0.z>>2), uzf = (float)(q0.w>>2);
    float pbv[4];
    float pb2v = A[OF_PB2];
    #pragma unroll
    for (int g=0;g<4;++g) pbv[g] = pb2v;
    #pragma unroll 2
    for (int j=0;j<64;++j){
      float dj = ssc[j] - (saf[0][j]*uxf + saf[1][j]*uyf + saf[2][j]*uzf);
      float wj = w2s[j];
      float4 ea = *(const float4*)&e4T[j][0];
      pbv[0] += fmaxf(ea.x+dj,0.f)*wj; pbv[1] += fmaxf(ea.y+dj,0.f)*wj;
      pbv[2] += fmaxf(ea.z+dj,0.f)*wj; pbv[3] += fmaxf(ea.w+dj,0.f)*wj;
    }
    const float4* krow = (const float4*)(kb + (size_t)t*CD);
    float4 kc0 = krow[0], kc1 = krow[1], kc2 = krow[2], kc3 = krow[3];
    for (int h=0;h<HD;++h){
      int hn = (h+1)&7;
      float4 kn0 = krow[hn*4+0], kn1 = krow[hn*4+1];
      float4 kn2 = krow[hn*4+2], kn3 = krow[hn*4+3];
      float p[4];
      #pragma unroll
      for (int g=0;g<4;++g){
        const float* qg = &q4s[g][h*DHD];
        float dot = qg[0]*kc0.x + qg[1]*kc0.y + qg[2]*kc0.z + qg[3]*kc0.w
                  + qg[4]*kc1.x + qg[5]*kc1.y + qg[6]*kc1.z + qg[7]*kc1.w
                  + qg[8]*kc2.x + qg[9]*kc2.y + qg[10]*kc2.z + qg[11]*kc2.w
                  + qg[12]*kc3.x + qg[13]*kc3.y + qg[14]*kc3.z + qg[15]*kc3.w;
        p[g] = __expf(dot*0.25f + pbv[g]);
      }
      sc2[t][h*2]   = pack2(p[0],p[1]);
      sc2[t][h*2+1] = pack2(p[2],p[3]);
      kc0 = kn0; kc1 = kn1; kc2 = kn2; kc3 = kn3;
    }
  }
  __syncthreads();
  // denominators: wave g handles query g, all 8 heads
  {
    int g = t>>6, lane = t&63;
    int sel = g&1;
    for (int h=0;h<HD;++h){
      int col = h*2 + (g>>1);
      unsigned ua = sc2[lane][col];
      unsigned ub = sc2[lane+64][col];
      unsigned uc = sc2[lane+128][col];
      unsigned ud = sc2[lane+192][col];
      float s0 = sel ? (unhi(ua)+unhi(ub)+unhi(uc)+unhi(ud))
                     : (unlo(ua)+unlo(ub)+unlo(uc)+unlo(ud));
      #pragma unroll
      for (int o=32;o;o>>=1) s0 += __shfl_xor(s0,o,64);
      if (lane==0) rinv[g*8+h] = 1.f/s0;
    }
  }
  __syncthreads();
  // PV: 8-wide manual unroll, 8 coalesced loads in flight
  {
    int half=t>>7, c=t&127, h=c>>4;
    const float* vcol = vb + c;
    float acc[4]={0.f,0.f,0.f,0.f};
    #pragma unroll 2
    for (int s0=half*128; s0<half*128+128; s0+=8){
      float v0=vcol[(s0+0)*CD], v1=vcol[(s0+1)*CD], v2=vcol[(s0+2)*CD], v3=vcol[(s0+3)*CD];
      float v4=vcol[(s0+4)*CD], v5=vcol[(s0+5)*CD], v6=vcol[(s0+6)*CD], v7=vcol[(s0+7)*CD];
      uint2 u0=*(const uint2*)&sc2[s0+0][h*2];
      uint2 u1=*(const uint2*)&sc2[s0+1][h*2];
      uint2 u2=*(const uint2*)&sc2[s0+2][h*2];
      uint2 u3=*(const uint2*)&sc2[s0+3][h*2];
      uint2 u4=*(const uint2*)&sc2[s0+4][h*2];
      uint2 u5=*(const uint2*)&sc2[s0+5][h*2];
      uint2 u6=*(const uint2*)&sc2[s0+6][h*2];
      uint2 u7=*(const uint2*)&sc2[s0+7][h*2];
      acc[0] += unlo(u0.x)*v0 + unlo(u1.x)*v1 + unlo(u2.x)*v2 + unlo(u3.x)*v3
              + unlo(u4.x)*v4 + unlo(u5.x)*v5 + unlo(u6.x)*v6 + unlo(u7.x)*v7;
      acc[1] += unhi(u0.x)*v0 + unhi(u1.x)*v1 + unhi(u2.x)*v2 + unhi(u3.x)*v3
              + unhi(u4.x)*v4 + unhi(u5.x)*v5 + unhi(u6.x)*v6 + unhi(u7.x)*v7;
      acc[2] += unlo(u0.y)*v0 + unlo(u1.y)*v1 + unlo(u2.y)*v2 + unlo(u3.y)*v3
              + unlo(u4.y)*v4 + unlo(u5.y)*v5 + unlo(u6.y)*v6 + unlo(u7.y)*v7;
      acc[3] += unhi(u0.y)*v0 + unhi(u1.y)*v1 + unhi(u2.y)*v2 + unhi(u3.y)*v3
              + unhi(u4.y)*v4 + unhi(u5.y)*v5 + unhi(u6.y)*v6 + unhi(u7.y)*v7;
    }
    #pragma unroll
    for (int g=0;g<4;++g) cpart[half][g][c]=acc[g];
  }
  __syncthreads();
  if (t < CD){
    int h = t>>4;
    #pragma unroll
    for (int g=0;g<4;++g)
      ctxT[t*4+g] = (cpart[0][g][t]+cpart[1][g][t])*rinv[g*8+h];
  }
  __syncthreads();
  // wo
  {
    int half=t>>7, c=t&127;
    const float* wo = A + OF_WO;
    float acc[4]={0.f,0.f,0.f,0.f};
    #pragma unroll 4
    for (int i=half*64;i<half*64+64;++i){
      float wv = wo[i*CD+c];
      float4 r = *(const float4*)&ctxT[i*4];
      acc[0]+=r.x*wv; acc[1]+=r.y*wv; acc[2]+=r.z*wv; acc[3]+=r.w*wv;
    }
    #pragma unroll
    for (int g=0;g<4;++g) cpart[half][g][c]=acc[g];
  }
  __syncthreads();
  if (t < CD){
    float bov = A[OF_BO+t];
    #pragma unroll
    for (int g=0;g<4;++g)
      ctxT[t*4+g] = cpart[0][g][t]+cpart[1][g][t] + bov
                  + A[OF_FEAT + (size_t)(n0+g)*CD + t];
  }
  __syncthreads();
  // LayerNorm: wave g handles row g
  {
    int g = t>>6, lane = t&63;
    float x0 = ctxT[lane*4+g], x1 = ctxT[(lane+64)*4+g];
    float s1 = x0+x1, s2 = x0*x0+x1*x1;
    #pragma unroll
    for (int o=32;o;o>>=1){ s1 += __shfl_xor(s1,o,64); s2 += __shfl_xor(s2,o,64); }
    float mean = s1*(1.f/128.f);
    float var  = s2*(1.f/128.f) - mean*mean;
    float rs = rsqrtf(var + EPSF);
    yb[(size_t)(n0+g)*CD + lane]    = (x0-mean)*rs*A[OF_LNG+lane]    + A[OF_LNB+lane];
    yb[(size_t)(n0+g)*CD + lane+64] = (x1-mean)*rs*A[OF_LNG+lane+64] + A[OF_LNB+lane+64];
  }
}

// ========== K10: SubMConv3d, 8 voxels/block (512 blocks), weights hoisted ==========
__global__ __launch_bounds__(256) void k10_conv(const int* idx, const int* map,
    const float* yb, const float* A, const float* wt, const int* flag, void* outv)
{
  __shared__ int sco4[8][4];
  __shared__ int jn[8][27];
  __shared__ float partial[4][8][NCD];
  int t = threadIdx.x;
  int p0 = blockIdx.x*8;
  if (t < 32) ((int*)sco4)[t] = idx[4*p0 + t];
  __syncthreads();
  if (t < 216){
    int v = t/27, nb = t - v*27;
    int kd = nb/9, kh = (nb/3)%3, kw = nb%3;
    int bb = sco4[v][0];
    int nx = sco4[v][1]+kd-1, ny = sco4[v][2]+kh-1, nz = sco4[v][3]+kw-1;
    int j = -1;
    if ((unsigned)nx < XD && (unsigned)ny < YD && (unsigned)nz < ZD)
      j = map[((bb*XD+nx)*YD+ny)*ZD+nz];
    jn[v][nb] = j;
  }
  __syncthreads();
  int w = t>>6, l = t&63;
  int og = l & 3, cg = l >> 2;
  int c0 = cg*8;
  float acc[8][5];
  #pragma unroll
  for (int v=0;v<8;++v)
    #pragma unroll
    for (int oo=0;oo<5;++oo) acc[v][oo]=0.f;
  for (int nb = w; nb < 27; nb += 4){
    const float* wbase = wt + (size_t)nb*NCD*CD + c0;
    float4 wreg[10];
    #pragma unroll
    for (int oo=0;oo<5;++oo){
      wreg[oo*2]   = *(const float4*)(wbase + (size_t)(og*5+oo)*CD);
      wreg[oo*2+1] = *(const float4*)(wbase + (size_t)(og*5+oo)*CD + 4);
    }
    #pragma unroll
    for (int v=0; v<8; ++v){
      int j = jn[v][nb];
      if (j < 0) continue;
      const float4* y4 = (const float4*)(yb + (size_t)j*CD + c0);
      float4 ya = y4[0], ybb = y4[1];
      #pragma unroll
      for (int oo=0;oo<5;++oo){
        float4 wa = wreg[oo*2], wb = wreg[oo*2+1];
        acc[v][oo] += ya.x*wa.x + ya.y*wa.y + ya.z*wa.z + ya.w*wa.w
                    + ybb.x*wb.x + ybb.y*wb.y + ybb.z*wb.z + ybb.w*wb.w;
      }
    }
  }
  #pragma unroll
  for (int v=0;v<8;++v)
    #pragma unroll
    for (int oo=0;oo<5;++oo){
      float s = acc[v][oo];
      s += __shfl_xor(s, 4, 64);
      s += __shfl_xor(s, 8, 64);
      s += __shfl_xor(s, 16, 64);
      s += __shfl_xor(s, 32, 64);
      if (cg == 0) partial[w][v][og*5+oo] = s;
    }
  __syncthreads();
  if (t < 160){
    int v = t/20, o = t - v*20;
    float s = partial[0][v][o]+partial[1][v][o]+partial[2][v][o]+partial[3][v][o]
            + A[OF_SEGB+o];
    if (*flag) ((ushort_t*)outv)[(size_t)(p0+v)*NCD + o] = f2bf(s);
    else       ((float*)outv)[(size_t)(p0+v)*NCD + o]   = s;
  }
}

// ---------------- launch ----------------
extern "C" void kernel_launch(void* const* d_in, const int* in_sizes, int n_in,
                              void* d_out, int out_size, void* d_ws, size_t ws_size,
                              hipStream_t stream) {
  const int* idx = (const int*)d_in[0];

  char* w = (char*)d_ws;
  size_t off = 0;
  #define ALLOC(name, type, count) \
    type* name = (type*)(w + off); off += (((size_t)(count)*sizeof(type)) + 255) & ~(size_t)255;
  ALLOC(flag,   int,   64)
  ALLOC(arena,  float, ARENA_N)
  ALLOC(wt,     float, 27*NCD*CD)
  ALLOC(map,    int,   MAPN)
  ALLOC(afold,  float, 192)
  ALLOC(scfold, float, 64)
  ALLOC(t1T,    float, CD*NSV)
  ALLOC(kb,     float, NSV*CD)
  ALLOC(vbuf,   float, NSV*CD)
  ALLOC(qb,     float, NVOX*CD)
  ALLOC(yb,     float, NVOX*CD)
  #undef ALLOC
  (void)off; (void)ws_size; (void)n_in; (void)in_sizes; (void)out_size;

  SrcPtrs sp;
  for (int i=0;i<25;++i) sp.p[i] = d_in[i+1];

  kprep   <<<512, 512, 0, stream>>>(sp, idx, flag, arena, wt, map, afold, scfold, qb, t1T);
  k6_fused<<<NSV, 256, 0, stream>>>(t1T, arena, idx, map, kb, vbuf);
  k9_attn <<<NVOX/4, 256, 0, stream>>>(arena, idx, afold, scfold, kb, vbuf, qb, yb);
  k10_conv<<<NVOX/8, 256, 0, stream>>>(idx, map, yb, arena, wt, flag, d_out);
}